// Round 1
// baseline (6666.043 us; speedup 1.0000x reference)
//
#include <hip/hip_runtime.h>
#include <hip/hip_bf16.h>

// ---------------------------------------------------------------------------
// PoseFeatureNet: GCN(2 layer, agg only on batch0 of pose1) -> biLSTM -> head
// Round 1: correctness-first fp32-compute baseline.
//   - feats / pre / Whh_T stored bf16 (storage rounding only, accum fp32)
//   - backward LSTM reduced to a single step (hs_b[-1] == one step on x[T-1])
// ---------------------------------------------------------------------------

#define TT 256
#define BB 128
#define NNODE 17
#define HH 128
#define DD 2176    // 17*128
#define LHID 256
#define G4 1024    // 4*LHID
#define NCLS 625

__device__ __constant__ int ESRC[19] = {15,13,16,14,11,5,6,5,5,6,7,8,1,0,0,1,2,3,4};
__device__ __constant__ int EDST[19] = {13,11,14,12,12,11,12,6,7,8,9,10,2,1,2,3,4,5,6};
__device__ __constant__ float DEGF[17] = {1,2,3,2,2,2,3,2,2,2,2,3,4,2,2,1,1};

__device__ inline float lo2f(unsigned u){ union{unsigned x; float f;} c; c.x = u << 16; return c.f; }
__device__ inline float hi2f(unsigned u){ union{unsigned x; float f;} c; c.x = u & 0xffff0000u; return c.f; }
__device__ inline unsigned short f2b(float f){
    __hip_bfloat16 h = __float2bfloat16(f);
    unsigned short s; __builtin_memcpy(&s, &h, 2); return s;
}
__device__ inline unsigned pack2(float a, float b){
    return (unsigned)f2b(a) | ((unsigned)f2b(b) << 16);
}
__device__ inline float sigm(float x){ return 1.f / (1.f + expf(-x)); }

// ---------------------------------------------------------------- AHAT (17x17)
__global__ void k_ahat(float* __restrict__ Ahat){
    int tid = threadIdx.x;
    if (tid < 289){
        int i = tid / 17, j = tid % 17;
        float a = (i == j) ? 1.0f / DEGF[i] : 0.0f;
        for (int e = 0; e < 19; ++e)
            if (EDST[e] == i && ESRC[e] == j)
                a += 1.0f / sqrtf(DEGF[i] * DEGF[j]);
        Ahat[tid] = a;
    }
}

// ------------------------------------------- Whh (1024x256) -> bf16 T (256x1024)
__global__ void k_whh_t(const float* __restrict__ Whh, __hip_bfloat16* __restrict__ WT){
    int idx = blockIdx.x * 256 + threadIdx.x;   // 262144 total
    int n = idx >> 8, k = idx & 255;
    WT[k * G4 + n] = __float2bfloat16(Whh[idx]);
}

// ------------------------------------------------------------- fused GCN block
// block = one t (grid 256), 1024 threads, loops over b=0..127.
__global__ __launch_bounds__(1024) void k_gcn(
    const float* __restrict__ pose1, const float* __restrict__ pose2,
    const float* __restrict__ W1, const float* __restrict__ b1,
    const float* __restrict__ W2, const float* __restrict__ b2,
    const float* __restrict__ Ahat, __hip_bfloat16* __restrict__ feats)
{
    __shared__ float W2s[128*128];
    __shared__ float W1s[3*128];
    __shared__ float b1s[128], b2s[128];
    __shared__ float As[289];
    __shared__ float ps1[51], ps2[51];
    __shared__ float bufA[NNODE*128];   // pose1 path
    __shared__ float bufB[NNODE*128];   // pose2 path

    const int tid = threadIdx.x;
    for (int i = tid; i < 128*128; i += 1024) W2s[i] = W2[i];
    if (tid < 384) W1s[tid] = W1[tid];
    if (tid < 128){ b1s[tid] = b1[tid]; b2s[tid] = b2[tid]; }
    if (tid >= 512 && tid < 512+289) As[tid-512] = Ahat[tid-512];
    __syncthreads();

    const int t  = blockIdx.x;
    const int h  = tid & 127;
    const int n0 = tid >> 7;           // 0..7, wave-uniform
    int nlist[3]; int nv = 0;
    for (int s = 0; s < 3; ++s){ int n = n0 + 8*s; if (n < NNODE) nlist[nv++] = n; }

    for (int b = 0; b < BB; ++b){
        if (tid < 51)                     ps1[tid]    = pose1[(size_t)(b*TT + t)*51 + tid];
        else if (tid >= 64 && tid < 115)  ps2[tid-64] = pose2[(size_t)(b*TT + t)*51 + (tid-64)];
        __syncthreads();

        // ----- layer 1
        for (int s = 0; s < nv; ++s){
            int n = nlist[s];
            float a1 = ps1[n*3+0]*W1s[h] + ps1[n*3+1]*W1s[128+h] + ps1[n*3+2]*W1s[256+h];
            float a2 = ps2[n*3+0]*W1s[h] + ps2[n*3+1]*W1s[128+h] + ps2[n*3+2]*W1s[256+h];
            bufB[n*128+h] = fmaxf(a2 + b1s[h], 0.f);
            bufA[n*128+h] = (b == 0) ? a1 : fmaxf(a1 + b1s[h], 0.f);
        }
        __syncthreads();
        if (b == 0){   // aggregate raw g1, then bias+relu
            float r[3];
            for (int s = 0; s < nv; ++s){
                int n = nlist[s]; float a = 0.f;
                #pragma unroll
                for (int j = 0; j < NNODE; ++j) a += As[n*17+j] * bufA[j*128+h];
                r[s] = a;
            }
            __syncthreads();
            for (int s = 0; s < nv; ++s) bufA[nlist[s]*128+h] = fmaxf(r[s] + b1s[h], 0.f);
            __syncthreads();
        }

        // ----- layer 2
        float u1[3] = {0,0,0}, u2[3] = {0,0,0};
        #pragma unroll 4
        for (int k = 0; k < 128; k += 4){
            float w0 = W2s[(k+0)*128+h], w1 = W2s[(k+1)*128+h];
            float w2 = W2s[(k+2)*128+h], w3 = W2s[(k+3)*128+h];
            for (int s = 0; s < nv; ++s){
                int n = nlist[s];
                float4 a1 = *(const float4*)&bufA[n*128+k];
                float4 a2 = *(const float4*)&bufB[n*128+k];
                u1[s] += a1.x*w0 + a1.y*w1 + a1.z*w2 + a1.w*w3;
                u2[s] += a2.x*w0 + a2.y*w1 + a2.z*w2 + a2.w*w3;
            }
        }
        float v1[3];
        if (b == 0){
            __syncthreads();
            for (int s = 0; s < nv; ++s) bufA[nlist[s]*128+h] = u1[s];
            __syncthreads();
            for (int s = 0; s < nv; ++s){
                int n = nlist[s]; float a = 0.f;
                #pragma unroll
                for (int j = 0; j < NNODE; ++j) a += As[n*17+j] * bufA[j*128+h];
                v1[s] = a;
            }
        } else { v1[0] = u1[0]; v1[1] = u1[1]; v1[2] = u1[2]; }

        const size_t fbase = ((size_t)t*BB + b) * DD;
        for (int s = 0; s < nv; ++s){
            int n = nlist[s];
            feats[fbase + n*128 + h] = __float2bfloat16(0.5f*(v1[s] + u2[s]) + b2s[h]);
        }
        __syncthreads();  // protect ps/buf reuse next b
    }
}

// ----------------------------------------------- pre GEMM: C = A @ Bw^T + bias
// A: M x 2176 bf16 (row-major), Bw: 1024 x 2176 fp32, C: M x 1024 bf16
// grid (M/128, 8), 256 threads, 128x128 tile, 8x8 microtile, fp32 accum.
__global__ __launch_bounds__(256) void k_gemm_pre(
    const __hip_bfloat16* __restrict__ A, const float* __restrict__ Bw,
    const float* __restrict__ bi1, const float* __restrict__ bi2,
    __hip_bfloat16* __restrict__ C)
{
    __shared__ float Asm[16][128];
    __shared__ float Bsm[16][128];
    const int tid = threadIdx.x;
    const size_t m0 = (size_t)blockIdx.x * 128;
    const int n0 = blockIdx.y * 128;
    const int tx = tid & 15, ty = tid >> 4;
    const int lr = tid >> 1, lk = (tid & 1) * 8;
    const unsigned short* Ab = (const unsigned short*)A;

    float acc[8][8];
    #pragma unroll
    for (int i = 0; i < 8; ++i)
        #pragma unroll
        for (int j = 0; j < 8; ++j) acc[i][j] = 0.f;

    for (int kt = 0; kt < DD; kt += 16){
        uint4 av = *(const uint4*)(Ab + (m0 + lr)*DD + kt + lk);
        Asm[lk+0][lr] = lo2f(av.x); Asm[lk+1][lr] = hi2f(av.x);
        Asm[lk+2][lr] = lo2f(av.y); Asm[lk+3][lr] = hi2f(av.y);
        Asm[lk+4][lr] = lo2f(av.z); Asm[lk+5][lr] = hi2f(av.z);
        Asm[lk+6][lr] = lo2f(av.w); Asm[lk+7][lr] = hi2f(av.w);
        const float* bp = Bw + (size_t)(n0 + lr)*DD + kt + lk;
        float4 bv0 = *(const float4*)bp;
        float4 bv1 = *(const float4*)(bp + 4);
        Bsm[lk+0][lr] = bv0.x; Bsm[lk+1][lr] = bv0.y; Bsm[lk+2][lr] = bv0.z; Bsm[lk+3][lr] = bv0.w;
        Bsm[lk+4][lr] = bv1.x; Bsm[lk+5][lr] = bv1.y; Bsm[lk+6][lr] = bv1.z; Bsm[lk+7][lr] = bv1.w;
        __syncthreads();
        #pragma unroll
        for (int k = 0; k < 16; ++k){
            float4 a0 = *(const float4*)&Asm[k][ty*8];
            float4 a1 = *(const float4*)&Asm[k][ty*8+4];
            float4 b0 = *(const float4*)&Bsm[k][tx*8];
            float4 b1 = *(const float4*)&Bsm[k][tx*8+4];
            float ar[8] = {a0.x,a0.y,a0.z,a0.w,a1.x,a1.y,a1.z,a1.w};
            float br[8] = {b0.x,b0.y,b0.z,b0.w,b1.x,b1.y,b1.z,b1.w};
            #pragma unroll
            for (int i = 0; i < 8; ++i)
                #pragma unroll
                for (int j = 0; j < 8; ++j) acc[i][j] += ar[i]*br[j];
        }
        __syncthreads();
    }
    float bias[8];
    #pragma unroll
    for (int j = 0; j < 8; ++j){ int n = n0 + tx*8 + j; bias[j] = bi1[n] + bi2[n]; }
    unsigned short* Cb = (unsigned short*)C;
    #pragma unroll
    for (int i = 0; i < 8; ++i){
        size_t row = m0 + ty*8 + i;
        uint4 o;
        o.x = pack2(acc[i][0]+bias[0], acc[i][1]+bias[1]);
        o.y = pack2(acc[i][2]+bias[2], acc[i][3]+bias[3]);
        o.z = pack2(acc[i][4]+bias[4], acc[i][5]+bias[5]);
        o.w = pack2(acc[i][6]+bias[6], acc[i][7]+bias[7]);
        *(uint4*)(Cb + row*G4 + n0 + tx*8) = o;
    }
}

// ------------------------------- backward LSTM = single step from zero state
__global__ void k_lstm_b1(const __hip_bfloat16* __restrict__ preb, float* __restrict__ h_b){
    int idx = blockIdx.x * 256 + threadIdx.x;   // 32768
    int b = idx >> 8, j = idx & 255;
    const __hip_bfloat16* z = preb + (size_t)b * G4;
    float zi = __bfloat162float(z[j]);
    float zg = __bfloat162float(z[512 + j]);
    float zo = __bfloat162float(z[768 + j]);
    float c = sigm(zi) * tanhf(zg);            // f-gate * c0 = 0
    h_b[(size_t)b*LHID + j] = sigm(zo) * tanhf(c);
}

// ------------------------------------ forward LSTM scan: 64 WGs x 2 samples
__global__ __launch_bounds__(256) void k_lstm_f(
    const __hip_bfloat16* __restrict__ pre,   // (256,128,1024) bf16
    const __hip_bfloat16* __restrict__ WT,    // (256,1024) bf16 = Whh^T
    float* __restrict__ hout)                 // (128,256)
{
    __shared__ float hls[2][LHID];
    __shared__ float zls[2][G4];
    const int tid = threadIdx.x;
    const int s0 = blockIdx.x * 2;
    const unsigned short* preb = (const unsigned short*)pre;
    const unsigned short* wtb  = (const unsigned short*)WT;
    float c0 = 0.f, c1 = 0.f, hn0 = 0.f, hn1 = 0.f;
    hls[0][tid] = 0.f; hls[1][tid] = 0.f;
    __syncthreads();
    const int n4 = tid * 4;

    for (int t = 0; t < TT; ++t){
        float z0[4], z1[4];
        {
            const unsigned short* p = preb + ((size_t)t*BB + s0)*G4 + n4;
            uint2 a = *(const uint2*)p;
            uint2 bq = *(const uint2*)(p + G4);
            z0[0]=lo2f(a.x);  z0[1]=hi2f(a.x);  z0[2]=lo2f(a.y);  z0[3]=hi2f(a.y);
            z1[0]=lo2f(bq.x); z1[1]=hi2f(bq.x); z1[2]=lo2f(bq.y); z1[3]=hi2f(bq.y);
        }
        #pragma unroll 4
        for (int k = 0; k < LHID; k += 4){
            float4 h0 = *(const float4*)&hls[0][k];
            float4 h1 = *(const float4*)&hls[1][k];
            uint2 w;
            w = *(const uint2*)(wtb + (size_t)(k+0)*G4 + n4);
            { float w0=lo2f(w.x),w1=hi2f(w.x),w2=lo2f(w.y),w3=hi2f(w.y);
              z0[0]+=h0.x*w0; z0[1]+=h0.x*w1; z0[2]+=h0.x*w2; z0[3]+=h0.x*w3;
              z1[0]+=h1.x*w0; z1[1]+=h1.x*w1; z1[2]+=h1.x*w2; z1[3]+=h1.x*w3; }
            w = *(const uint2*)(wtb + (size_t)(k+1)*G4 + n4);
            { float w0=lo2f(w.x),w1=hi2f(w.x),w2=lo2f(w.y),w3=hi2f(w.y);
              z0[0]+=h0.y*w0; z0[1]+=h0.y*w1; z0[2]+=h0.y*w2; z0[3]+=h0.y*w3;
              z1[0]+=h1.y*w0; z1[1]+=h1.y*w1; z1[2]+=h1.y*w2; z1[3]+=h1.y*w3; }
            w = *(const uint2*)(wtb + (size_t)(k+2)*G4 + n4);
            { float w0=lo2f(w.x),w1=hi2f(w.x),w2=lo2f(w.y),w3=hi2f(w.y);
              z0[0]+=h0.z*w0; z0[1]+=h0.z*w1; z0[2]+=h0.z*w2; z0[3]+=h0.z*w3;
              z1[0]+=h1.z*w0; z1[1]+=h1.z*w1; z1[2]+=h1.z*w2; z1[3]+=h1.z*w3; }
            w = *(const uint2*)(wtb + (size_t)(k+3)*G4 + n4);
            { float w0=lo2f(w.x),w1=hi2f(w.x),w2=lo2f(w.y),w3=hi2f(w.y);
              z0[0]+=h0.w*w0; z0[1]+=h0.w*w1; z0[2]+=h0.w*w2; z0[3]+=h0.w*w3;
              z1[0]+=h1.w*w0; z1[1]+=h1.w*w1; z1[2]+=h1.w*w2; z1[3]+=h1.w*w3; }
        }
        *(float4*)&zls[0][n4] = make_float4(z0[0], z0[1], z0[2], z0[3]);
        *(float4*)&zls[1][n4] = make_float4(z1[0], z1[1], z1[2], z1[3]);
        __syncthreads();
        {
            float i0=zls[0][tid], f0=zls[0][256+tid], g0=zls[0][512+tid], o0=zls[0][768+tid];
            float i1=zls[1][tid], f1=zls[1][256+tid], g1=zls[1][512+tid], o1=zls[1][768+tid];
            c0 = sigm(f0)*c0 + sigm(i0)*tanhf(g0);  hn0 = sigm(o0)*tanhf(c0);
            c1 = sigm(f1)*c1 + sigm(i1)*tanhf(g1);  hn1 = sigm(o1)*tanhf(c1);
            hls[0][tid] = hn0;  hls[1][tid] = hn1;
        }
        __syncthreads();
    }
    hout[(size_t)s0*LHID + tid]     = hn0;
    hout[(size_t)(s0+1)*LHID + tid] = hn1;
}

// ----------------------------------------------------- head: pool + classifier
__global__ __launch_bounds__(256) void k_head(
    const float* __restrict__ h_f, const float* __restrict__ h_b,
    const float* __restrict__ Wc, const float* __restrict__ bc,
    float* __restrict__ out)
{
    __shared__ float pool[512];
    const int b = blockIdx.x, tid = threadIdx.x;
    float p0 = fmaxf(h_f[(size_t)b*LHID + tid], 0.f);
    float p1 = fmaxf(h_b[(size_t)b*LHID + tid], 0.f);
    pool[tid] = p0; pool[256 + tid] = p1;
    out[(size_t)b*512 + tid]       = p0;
    out[(size_t)b*512 + 256 + tid] = p1;
    __syncthreads();
    for (int n = tid; n < NCLS; n += 256){
        float a = bc[n];
        const float* w = Wc + (size_t)n * 512;
        #pragma unroll 4
        for (int k = 0; k < 512; k += 4){
            float4 wv = *(const float4*)(w + k);
            a += pool[k]*wv.x + pool[k+1]*wv.y + pool[k+2]*wv.z + pool[k+3]*wv.w;
        }
        out[(size_t)BB*512 + (size_t)b*NCLS + n] = a;
    }
}

// ---------------------------------------------------------------------------
extern "C" void kernel_launch(void* const* d_in, const int* in_sizes, int n_in,
                              void* d_out, int out_size, void* d_ws, size_t ws_size,
                              hipStream_t stream) {
    const float* pose1 = (const float*)d_in[0];
    const float* pose2 = (const float*)d_in[1];
    const float* W1    = (const float*)d_in[2];
    const float* b1    = (const float*)d_in[3];
    const float* W2    = (const float*)d_in[4];
    const float* b2    = (const float*)d_in[5];
    const float* Wih_f = (const float*)d_in[6];
    const float* Whh_f = (const float*)d_in[7];
    const float* bih_f = (const float*)d_in[8];
    const float* bhh_f = (const float*)d_in[9];
    const float* Wih_b = (const float*)d_in[10];
    const float* Whh_b = (const float*)d_in[11];  // unused beyond 1 step (h0=0)
    const float* bih_b = (const float*)d_in[12];
    const float* bhh_b = (const float*)d_in[13];
    const float* Wc    = (const float*)d_in[14];
    const float* bc    = (const float*)d_in[15];
    (void)Whh_b; (void)in_sizes; (void)n_in; (void)out_size; (void)ws_size;
    float* out = (float*)d_out;
    char* ws = (char*)d_ws;

    // workspace layout (bytes)
    float*           Ahat  = (float*)(ws + 0);                    //   1,156
    __hip_bfloat16*  WT    = (__hip_bfloat16*)(ws + 4096);        // 524,288
    float*           h_b   = (float*)(ws + 528384);               // 131,072
    float*           h_f   = (float*)(ws + 659456);               // 131,072
    __hip_bfloat16*  pre_b = (__hip_bfloat16*)(ws + 790528);      // 262,144
    __hip_bfloat16*  feats = (__hip_bfloat16*)(ws + 2097152);     // 142,606,336
    __hip_bfloat16*  pre_f = (__hip_bfloat16*)(ws + 144703488);   //  67,108,864
    // total ~202 MB

    k_ahat  <<<1, 512, 0, stream>>>(Ahat);
    k_whh_t <<<1024, 256, 0, stream>>>(Whh_f, WT);
    k_gcn   <<<256, 1024, 0, stream>>>(pose1, pose2, W1, b1, W2, b2, Ahat, feats);
    k_gemm_pre<<<dim3(256, 8), 256, 0, stream>>>(feats, Wih_f, bih_f, bhh_f, pre_f);
    k_gemm_pre<<<dim3(1, 8), 256, 0, stream>>>(feats + (size_t)255*BB*DD, Wih_b, bih_b, bhh_b, pre_b);
    k_lstm_b1<<<128, 256, 0, stream>>>(pre_b, h_b);
    k_lstm_f <<<64, 256, 0, stream>>>(pre_f, WT, h_f);
    k_head  <<<128, 256, 0, stream>>>(h_f, h_b, Wc, bc, out);
}

// Round 2
// 4765.382 us; speedup vs baseline: 1.3988x; 1.3988x over previous
//
#include <hip/hip_runtime.h>
#include <hip/hip_bf16.h>

// ---------------------------------------------------------------------------
// PoseFeatureNet R2:
//  - pre_f GEMM moved to bf16 MFMA (16x16x32), m97-style 128x128 tile, BK=32
//  - backward LSTM fused to wave-per-(b,j) dot kernel (pre_b eliminated)
//  - forward LSTM scan: 512 thr (2 waves/SIMD), k-split 2, unroll 8
// ---------------------------------------------------------------------------

#define TT 256
#define BB 128
#define NNODE 17
#define HH 128
#define DD 2176    // 17*128
#define LHID 256
#define G4 1024    // 4*LHID
#define NCLS 625

__device__ __constant__ int ESRC[19] = {15,13,16,14,11,5,6,5,5,6,7,8,1,0,0,1,2,3,4};
__device__ __constant__ int EDST[19] = {13,11,14,12,12,11,12,6,7,8,9,10,2,1,2,3,4,5,6};
__device__ __constant__ float DEGF[17] = {1,2,3,2,2,2,3,2,2,2,2,3,4,2,2,1,1};

__device__ inline float lo2f(unsigned u){ union{unsigned x; float f;} c; c.x = u << 16; return c.f; }
__device__ inline float hi2f(unsigned u){ union{unsigned x; float f;} c; c.x = u & 0xffff0000u; return c.f; }
__device__ inline unsigned short f2b(float f){
    __hip_bfloat16 h = __float2bfloat16(f);
    unsigned short s; __builtin_memcpy(&s, &h, 2); return s;
}
__device__ inline unsigned pack2(float a, float b){
    return (unsigned)f2b(a) | ((unsigned)f2b(b) << 16);
}
__device__ inline float sigm(float x){ return 1.f / (1.f + expf(-x)); }

typedef __attribute__((ext_vector_type(8))) short bf16x8;
typedef __attribute__((ext_vector_type(4))) float f32x4;

__device__ inline void gload16(const void* g, void* l){
    __builtin_amdgcn_global_load_lds(
        (const __attribute__((address_space(1))) void*)g,
        (__attribute__((address_space(3))) void*)l, 16, 0, 0);
}

// ---------------------------------------------------------------- AHAT (17x17)
__global__ void k_ahat(float* __restrict__ Ahat){
    int tid = threadIdx.x;
    if (tid < 289){
        int i = tid / 17, j = tid % 17;
        float a = (i == j) ? 1.0f / DEGF[i] : 0.0f;
        for (int e = 0; e < 19; ++e)
            if (EDST[e] == i && ESRC[e] == j)
                a += 1.0f / sqrtf(DEGF[i] * DEGF[j]);
        Ahat[tid] = a;
    }
}

// ------------------------------------------- Whh (1024x256) -> bf16 T (256x1024)
__global__ void k_whh_t(const float* __restrict__ Whh, __hip_bfloat16* __restrict__ WT){
    int idx = blockIdx.x * 256 + threadIdx.x;   // 262144 total
    int n = idx >> 8, k = idx & 255;
    WT[k * G4 + n] = __float2bfloat16(Whh[idx]);
}

// ------------------------------------------------------------- fused GCN block
__global__ __launch_bounds__(1024) void k_gcn(
    const float* __restrict__ pose1, const float* __restrict__ pose2,
    const float* __restrict__ W1, const float* __restrict__ b1,
    const float* __restrict__ W2, const float* __restrict__ b2,
    const float* __restrict__ Ahat, __hip_bfloat16* __restrict__ feats)
{
    __shared__ float W2s[128*128];
    __shared__ float W1s[3*128];
    __shared__ float b1s[128], b2s[128];
    __shared__ float As[289];
    __shared__ float ps1[51], ps2[51];
    __shared__ float bufA[NNODE*128];
    __shared__ float bufB[NNODE*128];

    const int tid = threadIdx.x;
    for (int i = tid; i < 128*128; i += 1024) W2s[i] = W2[i];
    if (tid < 384) W1s[tid] = W1[tid];
    if (tid < 128){ b1s[tid] = b1[tid]; b2s[tid] = b2[tid]; }
    if (tid >= 512 && tid < 512+289) As[tid-512] = Ahat[tid-512];
    __syncthreads();

    const int t  = blockIdx.x;
    const int h  = tid & 127;
    const int n0 = tid >> 7;
    int nlist[3]; int nv = 0;
    for (int s = 0; s < 3; ++s){ int n = n0 + 8*s; if (n < NNODE) nlist[nv++] = n; }

    for (int b = 0; b < BB; ++b){
        if (tid < 51)                     ps1[tid]    = pose1[(size_t)(b*TT + t)*51 + tid];
        else if (tid >= 64 && tid < 115)  ps2[tid-64] = pose2[(size_t)(b*TT + t)*51 + (tid-64)];
        __syncthreads();

        for (int s = 0; s < nv; ++s){
            int n = nlist[s];
            float a1 = ps1[n*3+0]*W1s[h] + ps1[n*3+1]*W1s[128+h] + ps1[n*3+2]*W1s[256+h];
            float a2 = ps2[n*3+0]*W1s[h] + ps2[n*3+1]*W1s[128+h] + ps2[n*3+2]*W1s[256+h];
            bufB[n*128+h] = fmaxf(a2 + b1s[h], 0.f);
            bufA[n*128+h] = (b == 0) ? a1 : fmaxf(a1 + b1s[h], 0.f);
        }
        __syncthreads();
        if (b == 0){
            float r[3];
            for (int s = 0; s < nv; ++s){
                int n = nlist[s]; float a = 0.f;
                #pragma unroll
                for (int j = 0; j < NNODE; ++j) a += As[n*17+j] * bufA[j*128+h];
                r[s] = a;
            }
            __syncthreads();
            for (int s = 0; s < nv; ++s) bufA[nlist[s]*128+h] = fmaxf(r[s] + b1s[h], 0.f);
            __syncthreads();
        }

        float u1[3] = {0,0,0}, u2[3] = {0,0,0};
        #pragma unroll 4
        for (int k = 0; k < 128; k += 4){
            float w0 = W2s[(k+0)*128+h], w1 = W2s[(k+1)*128+h];
            float w2 = W2s[(k+2)*128+h], w3 = W2s[(k+3)*128+h];
            for (int s = 0; s < nv; ++s){
                int n = nlist[s];
                float4 a1 = *(const float4*)&bufA[n*128+k];
                float4 a2 = *(const float4*)&bufB[n*128+k];
                u1[s] += a1.x*w0 + a1.y*w1 + a1.z*w2 + a1.w*w3;
                u2[s] += a2.x*w0 + a2.y*w1 + a2.z*w2 + a2.w*w3;
            }
        }
        float v1[3];
        if (b == 0){
            __syncthreads();
            for (int s = 0; s < nv; ++s) bufA[nlist[s]*128+h] = u1[s];
            __syncthreads();
            for (int s = 0; s < nv; ++s){
                int n = nlist[s]; float a = 0.f;
                #pragma unroll
                for (int j = 0; j < NNODE; ++j) a += As[n*17+j] * bufA[j*128+h];
                v1[s] = a;
            }
        } else { v1[0] = u1[0]; v1[1] = u1[1]; v1[2] = u1[2]; }

        const size_t fbase = ((size_t)t*BB + b) * DD;
        for (int s = 0; s < nv; ++s){
            int n = nlist[s];
            feats[fbase + n*128 + h] = __float2bfloat16(0.5f*(v1[s] + u2[s]) + b2s[h]);
        }
        __syncthreads();
    }
}

// ------------------------------------------------- pre_f GEMM: bf16 MFMA
// A: (32768, 2176) bf16, Bw: (1024, 2176) fp32 -> staged bf16, C: (32768,1024) bf16
// grid (256, 8), 256 threads (4 waves), tile 128x128, BK=32, wave tile 64x64.
__global__ __launch_bounds__(256) void k_gemm_mfma(
    const __hip_bfloat16* __restrict__ A, const float* __restrict__ Bw,
    const float* __restrict__ bi1, const float* __restrict__ bi2,
    __hip_bfloat16* __restrict__ C)
{
    __shared__ unsigned short Asm[128][32];
    __shared__ unsigned short Bsm[128][32];
    const int tid = threadIdx.x;
    const int w = tid >> 6;
    const int l = tid & 63;
    const size_t m0 = (size_t)blockIdx.x * 128;
    const int n0 = blockIdx.y * 128;
    const int mw = (w >> 1) * 64;
    const int nw = (w & 1) * 64;

    f32x4 acc[4][4];
    #pragma unroll
    for (int s = 0; s < 4; ++s)
        #pragma unroll
        for (int t_ = 0; t_ < 4; ++t_)
            acc[s][t_] = (f32x4){0.f, 0.f, 0.f, 0.f};

    const unsigned short* Ab = (const unsigned short*)A;
    const int arow = w*32 + (l>>2);      // + {0,16}
    const int akoff = (l&3)*8;
    const int brow = w*32 + (l>>1);
    const int bko  = (l&1)*16;
    const int fr = l & 15, fq = (l >> 4) * 8;

    for (int kt = 0; kt < DD; kt += 32){
        // A tile: async global->LDS, 16B/lane, lane-linear layout
        gload16(Ab + (m0 + arow)*DD + kt + akoff,      &Asm[arow][akoff]);
        gload16(Ab + (m0 + arow + 16)*DD + kt + akoff, &Asm[arow+16][akoff]);
        // B tile: fp32 load + pack to bf16
        const float* bp = Bw + (size_t)(n0 + brow)*DD + kt + bko;
        float4 f0 = *(const float4*)bp;
        float4 f1 = *(const float4*)(bp+4);
        float4 f2 = *(const float4*)(bp+8);
        float4 f3 = *(const float4*)(bp+12);
        uint4 o0, o1;
        o0.x = pack2(f0.x,f0.y); o0.y = pack2(f0.z,f0.w);
        o0.z = pack2(f1.x,f1.y); o0.w = pack2(f1.z,f1.w);
        o1.x = pack2(f2.x,f2.y); o1.y = pack2(f2.z,f2.w);
        o1.z = pack2(f3.x,f3.y); o1.w = pack2(f3.z,f3.w);
        *(uint4*)&Bsm[brow][bko]   = o0;
        *(uint4*)&Bsm[brow][bko+8] = o1;
        __syncthreads();

        bf16x8 af[4], bf[4];
        #pragma unroll
        for (int s = 0; s < 4; ++s) af[s] = *(const bf16x8*)&Asm[mw + s*16 + fr][fq];
        #pragma unroll
        for (int t_ = 0; t_ < 4; ++t_) bf[t_] = *(const bf16x8*)&Bsm[nw + t_*16 + fr][fq];
        #pragma unroll
        for (int s = 0; s < 4; ++s)
            #pragma unroll
            for (int t_ = 0; t_ < 4; ++t_)
                acc[s][t_] = __builtin_amdgcn_mfma_f32_16x16x32_bf16(af[s], bf[t_], acc[s][t_], 0, 0, 0);
        __syncthreads();
    }

    const int cr = (l >> 4) * 4;
    const int cc = l & 15;
    unsigned short* Cb = (unsigned short*)C;
    #pragma unroll
    for (int t_ = 0; t_ < 4; ++t_){
        int col = n0 + nw + t_*16 + cc;
        float bias = bi1[col] + bi2[col];
        #pragma unroll
        for (int s = 0; s < 4; ++s)
            #pragma unroll
            for (int r = 0; r < 4; ++r){
                size_t row = m0 + mw + s*16 + cr + r;
                Cb[row*G4 + col] = f2b(acc[s][t_][r] + bias);
            }
    }
}

// --------------------- backward LSTM: one step from zero state, fully fused
// grid (128 b, 64), block 256 (4 waves); wave w -> j = blockIdx.y*4 + w
__global__ __launch_bounds__(256) void k_lstm_b(
    const __hip_bfloat16* __restrict__ feats255,   // (128, 2176) bf16
    const float* __restrict__ Wih_b,
    const float* __restrict__ bih_b, const float* __restrict__ bhh_b,
    float* __restrict__ h_b)
{
    __shared__ float fs[DD];
    const int tid = threadIdx.x;
    const int b = blockIdx.x;
    const unsigned* fbu = (const unsigned*)(feats255 + (size_t)b * DD);
    for (int i = tid; i < DD/2; i += 256){
        unsigned u = fbu[i];
        fs[2*i] = lo2f(u); fs[2*i+1] = hi2f(u);
    }
    __syncthreads();

    const int w = tid >> 6, lane = tid & 63;
    const int j = blockIdx.y * 4 + w;
    const float* Wi = Wih_b + (size_t)j * DD;
    const float* Wg = Wih_b + (size_t)(512 + j) * DD;
    const float* Wo = Wih_b + (size_t)(768 + j) * DD;
    float si = 0.f, sg = 0.f, so = 0.f;
    #pragma unroll 2
    for (int i = 0; i < 34; ++i){
        int k = lane + i*64;
        float f = fs[k];
        si += f * Wi[k]; sg += f * Wg[k]; so += f * Wo[k];
    }
    #pragma unroll
    for (int off = 32; off > 0; off >>= 1){
        si += __shfl_down(si, off);
        sg += __shfl_down(sg, off);
        so += __shfl_down(so, off);
    }
    if (lane == 0){
        float zi = si + bih_b[j]       + bhh_b[j];
        float zg = sg + bih_b[512 + j] + bhh_b[512 + j];
        float zo = so + bih_b[768 + j] + bhh_b[768 + j];
        float c = sigm(zi) * tanhf(zg);
        h_b[(size_t)b*LHID + j] = sigm(zo) * tanhf(c);
    }
}

// ------------------------- forward LSTM scan: 64 WGs x 2 samples, 512 threads
// k-split 2 (halves of hidden dim), col-split 256 (4 cols each, uint2 loads)
__global__ __launch_bounds__(512) void k_lstm_f(
    const __hip_bfloat16* __restrict__ pre,   // (256,128,1024) bf16
    const __hip_bfloat16* __restrict__ WT,    // (256,1024) bf16 = Whh^T [k][n]
    float* __restrict__ hout)                 // (128,256)
{
    __shared__ float hls[2][LHID];
    __shared__ float zp[2][2][G4];            // [khalf][sample][col] 32 KB
    const int tid = threadIdx.x;
    const int half = tid >> 8;
    const int cw = tid & 255;
    const int c0 = cw * 4;
    const int kbase = half * 128;
    const int s0 = blockIdx.x * 2;
    const unsigned short* preb = (const unsigned short*)pre;
    const unsigned short* wtb  = (const unsigned short*)WT;

    float cc0 = 0.f, cc1 = 0.f, hh0 = 0.f, hh1 = 0.f;
    if (tid < 256){ hls[0][tid] = 0.f; hls[1][tid] = 0.f; }
    __syncthreads();

    for (int t = 0; t < TT; ++t){
        float z0[4] = {0,0,0,0}, z1[4] = {0,0,0,0};
        if (half == 0){
            const unsigned short* p = preb + ((size_t)t*BB + s0)*G4 + c0;
            uint2 a  = *(const uint2*)p;
            uint2 bq = *(const uint2*)(p + G4);
            z0[0]=lo2f(a.x);  z0[1]=hi2f(a.x);  z0[2]=lo2f(a.y);  z0[3]=hi2f(a.y);
            z1[0]=lo2f(bq.x); z1[1]=hi2f(bq.x); z1[2]=lo2f(bq.y); z1[3]=hi2f(bq.y);
        }
        const unsigned short* wp = wtb + (size_t)kbase * G4 + c0;
        #pragma unroll 2
        for (int kb = 0; kb < 128; kb += 8){
            uint2 wv[8]; float ha[8], hb[8];
            #pragma unroll
            for (int u = 0; u < 8; ++u) wv[u] = *(const uint2*)(wp + (size_t)(kb+u)*G4);
            #pragma unroll
            for (int u = 0; u < 8; ++u){ ha[u] = hls[0][kbase+kb+u]; hb[u] = hls[1][kbase+kb+u]; }
            #pragma unroll
            for (int u = 0; u < 8; ++u){
                float w0=lo2f(wv[u].x), w1=hi2f(wv[u].x), w2=lo2f(wv[u].y), w3=hi2f(wv[u].y);
                z0[0]+=ha[u]*w0; z0[1]+=ha[u]*w1; z0[2]+=ha[u]*w2; z0[3]+=ha[u]*w3;
                z1[0]+=hb[u]*w0; z1[1]+=hb[u]*w1; z1[2]+=hb[u]*w2; z1[3]+=hb[u]*w3;
            }
        }
        *(float4*)&zp[half][0][c0] = make_float4(z0[0], z0[1], z0[2], z0[3]);
        *(float4*)&zp[half][1][c0] = make_float4(z1[0], z1[1], z1[2], z1[3]);
        __syncthreads();
        if (tid < 256){
            const int j = tid;
            float i0 = zp[0][0][j]     + zp[1][0][j];
            float f0 = zp[0][0][256+j] + zp[1][0][256+j];
            float g0 = zp[0][0][512+j] + zp[1][0][512+j];
            float o0 = zp[0][0][768+j] + zp[1][0][768+j];
            float i1 = zp[0][1][j]     + zp[1][1][j];
            float f1 = zp[0][1][256+j] + zp[1][1][256+j];
            float g1 = zp[0][1][512+j] + zp[1][1][512+j];
            float o1 = zp[0][1][768+j] + zp[1][1][768+j];
            cc0 = sigm(f0)*cc0 + sigm(i0)*tanhf(g0);  hh0 = sigm(o0)*tanhf(cc0);
            cc1 = sigm(f1)*cc1 + sigm(i1)*tanhf(g1);  hh1 = sigm(o1)*tanhf(cc1);
            hls[0][j] = hh0; hls[1][j] = hh1;
        }
        __syncthreads();
    }
    if (tid < 256){
        hout[(size_t)s0*LHID + tid]     = hh0;
        hout[(size_t)(s0+1)*LHID + tid] = hh1;
    }
}

// ----------------------------------------------------- head: pool + classifier
__global__ __launch_bounds__(256) void k_head(
    const float* __restrict__ h_f, const float* __restrict__ h_b,
    const float* __restrict__ Wc, const float* __restrict__ bc,
    float* __restrict__ out)
{
    __shared__ float pool[512];
    const int b = blockIdx.x, tid = threadIdx.x;
    float p0 = fmaxf(h_f[(size_t)b*LHID + tid], 0.f);
    float p1 = fmaxf(h_b[(size_t)b*LHID + tid], 0.f);
    pool[tid] = p0; pool[256 + tid] = p1;
    out[(size_t)b*512 + tid]       = p0;
    out[(size_t)b*512 + 256 + tid] = p1;
    __syncthreads();
    for (int n = tid; n < NCLS; n += 256){
        float a = bc[n];
        const float* w = Wc + (size_t)n * 512;
        #pragma unroll 4
        for (int k = 0; k < 512; k += 4){
            float4 wv = *(const float4*)(w + k);
            a += pool[k]*wv.x + pool[k+1]*wv.y + pool[k+2]*wv.z + pool[k+3]*wv.w;
        }
        out[(size_t)BB*512 + (size_t)b*NCLS + n] = a;
    }
}

// ---------------------------------------------------------------------------
extern "C" void kernel_launch(void* const* d_in, const int* in_sizes, int n_in,
                              void* d_out, int out_size, void* d_ws, size_t ws_size,
                              hipStream_t stream) {
    const float* pose1 = (const float*)d_in[0];
    const float* pose2 = (const float*)d_in[1];
    const float* W1    = (const float*)d_in[2];
    const float* b1    = (const float*)d_in[3];
    const float* W2    = (const float*)d_in[4];
    const float* b2    = (const float*)d_in[5];
    const float* Wih_f = (const float*)d_in[6];
    const float* Whh_f = (const float*)d_in[7];
    const float* bih_f = (const float*)d_in[8];
    const float* bhh_f = (const float*)d_in[9];
    const float* Wih_b = (const float*)d_in[10];
    const float* bih_b = (const float*)d_in[12];
    const float* bhh_b = (const float*)d_in[13];
    const float* Wc    = (const float*)d_in[14];
    const float* bc    = (const float*)d_in[15];
    (void)in_sizes; (void)n_in; (void)out_size; (void)ws_size;
    float* out = (float*)d_out;
    char* ws = (char*)d_ws;

    // workspace layout (bytes) — same footprint as R1 (<= 211,812,352)
    float*           Ahat  = (float*)(ws + 0);
    __hip_bfloat16*  WT    = (__hip_bfloat16*)(ws + 4096);        // 512 KB
    float*           h_b   = (float*)(ws + 528384);               // 128 KB
    float*           h_f   = (float*)(ws + 659456);               // 128 KB
    __hip_bfloat16*  feats = (__hip_bfloat16*)(ws + 2097152);     // 142,606,336
    __hip_bfloat16*  pre_f = (__hip_bfloat16*)(ws + 144703488);   //  67,108,864

    k_ahat  <<<1, 512, 0, stream>>>(Ahat);
    k_whh_t <<<1024, 256, 0, stream>>>(Whh_f, WT);
    k_gcn   <<<256, 1024, 0, stream>>>(pose1, pose2, W1, b1, W2, b2, Ahat, feats);
    k_gemm_mfma<<<dim3(256, 8), 256, 0, stream>>>(feats, Wih_f, bih_f, bhh_f, pre_f);
    k_lstm_b<<<dim3(128, 64), 256, 0, stream>>>(feats + (size_t)255*BB*DD, Wih_b, bih_b, bhh_b, h_b);
    k_lstm_f<<<64, 512, 0, stream>>>(pre_f, WT, h_f);
    k_head  <<<128, 256, 0, stream>>>(h_f, h_b, Wc, bc, out);
}

// Round 3
// 3322.801 us; speedup vs baseline: 2.0062x; 1.4341x over previous
//
#include <hip/hip_runtime.h>
#include <hip/hip_bf16.h>

// ---------------------------------------------------------------------------
// PoseFeatureNet R3:
//  - k_gcnfused: layer1 (VALU) + layer2 as 272x128x128 MFMA per (t, 16b) block,
//    using linearity: feats = (0.5*(r1 + r2))@W2 + b2, agg commutes with W2.
//  - k_lstm_f2: MFMA recurrence, 8 WGs x 16 samples, Whh streamed from L2 in
//    pre-packed fragment order, h as bf16 hi+lo split, c fp32 in regs.
//  - k_gemm_mfma unchanged (validated R2).
// ---------------------------------------------------------------------------

#define TT 256
#define BB 128
#define NNODE 17
#define DD 2176    // 17*128
#define LHID 256
#define G4 1024    // 4*LHID
#define NCLS 625

typedef unsigned short u16t;

__device__ __constant__ int ESRC[19] = {15,13,16,14,11,5,6,5,5,6,7,8,1,0,0,1,2,3,4};
__device__ __constant__ int EDST[19] = {13,11,14,12,12,11,12,6,7,8,9,10,2,1,2,3,4,5,6};
__device__ __constant__ float DEGF[17] = {1,2,3,2,2,2,3,2,2,2,2,3,4,2,2,1,1};

__device__ inline float lo2f(unsigned u){ union{unsigned x; float f;} c; c.x = u << 16; return c.f; }
__device__ inline float hi2f(unsigned u){ union{unsigned x; float f;} c; c.x = u & 0xffff0000u; return c.f; }
__device__ inline u16t f2b(float f){
    __hip_bfloat16 h = __float2bfloat16(f);
    u16t s; __builtin_memcpy(&s, &h, 2); return s;
}
__device__ inline float b2f(u16t s){ union{unsigned x; float f;} c; c.x = ((unsigned)s) << 16; return c.f; }
__device__ inline unsigned pack2(float a, float b){
    return (unsigned)f2b(a) | ((unsigned)f2b(b) << 16);
}
__device__ inline float sigm(float x){ return 1.f / (1.f + expf(-x)); }

typedef __attribute__((ext_vector_type(8))) short bf16x8;
typedef __attribute__((ext_vector_type(4))) float f32x4;

__device__ inline void gload16(const void* g, void* l){
    __builtin_amdgcn_global_load_lds(
        (const __attribute__((address_space(1))) void*)g,
        (__attribute__((address_space(3))) void*)l, 16, 0, 0);
}

// --------------------------------------------- W2 -> bf16 transposed [n][k]
__global__ void k_w2t(const float* __restrict__ W2, __hip_bfloat16* __restrict__ W2Tb){
    int g = blockIdx.x * 256 + threadIdx.x;   // 16384
    int k = g >> 7, n = g & 127;
    W2Tb[n * 128 + k] = __float2bfloat16(W2[g]);
}

// ------------------- Whh (1024x256) -> bf16 fragments in per-wave load order
// frag f = w*64 + kc*8 + nt  (w:8 waves, kc:8 k-chunks, nt:8 n-tiles/wave)
// lane l holds B[k = kc*32 + (l>>4)*8 + j][col = w*128 + nt*16 + (l&15)]
//        = Whh[col][k], stored at byte (f*64 + l)*16.
__global__ void k_wfrag(const float* __restrict__ Whh, __hip_bfloat16* __restrict__ WTfrag){
    int g = blockIdx.x * 256 + threadIdx.x;   // 32768
    int f = g >> 6, lane = g & 63;
    int w = f >> 6, kc = (f >> 3) & 7, nt = f & 7;
    int col = w * 128 + nt * 16 + (lane & 15);
    int k0  = kc * 32 + (lane >> 4) * 8;
    const float* src = Whh + (size_t)col * 256 + k0;
    float4 f0 = *(const float4*)src;
    float4 f1 = *(const float4*)(src + 4);
    uint4 o;
    o.x = pack2(f0.x, f0.y); o.y = pack2(f0.z, f0.w);
    o.z = pack2(f1.x, f1.y); o.w = pack2(f1.z, f1.w);
    *(uint4*)((char*)WTfrag + (size_t)g * 16) = o;
}

// ------------------------------------------------------------ fused GCN block
// grid 2048 = (t: 256) x (bc: 8), 512 threads. Block covers 16 (t,b) pairs.
// amix = 0.5*(r1 + r2) (b=0: 0.5*(A@r1 + r2)), feats = amix @ W2 + b2 via MFMA.
__global__ __launch_bounds__(512) void k_gcnfused(
    const float* __restrict__ pose1, const float* __restrict__ pose2,
    const float* __restrict__ W1, const float* __restrict__ b1,
    const float* __restrict__ b2, const __hip_bfloat16* __restrict__ W2Tb,
    __hip_bfloat16* __restrict__ feats)
{
    __shared__ u16t  Abuf[272][136];    // rows = n*16 + p, cols = k (pad 8)
    __shared__ u16t  BsmT[128][136];    // W2^T bf16, rows = n(out), cols = k
    __shared__ float ps4[2][16][17][4];
    __shared__ float araw[17*128];
    __shared__ float araw2[17*128];
    __shared__ float As[289];

    const int tid = threadIdx.x;
    const int blk = blockIdx.x;
    const int t   = blk >> 3;
    const int bc  = blk & 7;

    // ---- stage poses (16 pairs x 51 floats x 2)
    for (int idx = tid; idx < 1632; idx += 512){
        int p_ = idx >= 816 ? 1 : 0;
        int r  = idx - p_ * 816;
        int bl = r / 51, i = r - bl * 51;
        int n = i / 3, c = i - n * 3;
        const float* src = p_ ? pose2 : pose1;
        ps4[p_][bl][n][c] = src[(size_t)((bc*16 + bl) * TT + t) * 51 + i];
    }
    // ---- stage W2^T bf16 -> padded LDS
    {
        const uint4* src = (const uint4*)W2Tb;   // 16384 shorts = 2048 uint4
        for (int r = 0; r < 2; ++r){
            int f0 = (tid + r * 512) * 16;       // short index
            int n = f0 >> 7, k0 = f0 & 127;
            uint4 v0 = src[(tid + r*512)*2 + 0];
            uint4 v1 = src[(tid + r*512)*2 + 1];
            *(uint4*)&BsmT[n][k0]     = v0;
            *(uint4*)&BsmT[n][k0 + 8] = v1;
        }
    }
    // ---- Ahat (only needed by bc==0 blocks)
    if (bc == 0 && tid < 289){
        int i = tid / 17, j = tid - (tid/17)*17;
        float a = (i == j) ? 1.0f / DEGF[i] : 0.0f;
        for (int e = 0; e < 19; ++e)
            if (EDST[e] == i && ESRC[e] == j)
                a += 1.0f / sqrtf(DEGF[i] * DEGF[j]);
        As[tid] = a;
    }

    const int h = tid & 127;
    const int q = tid >> 7;            // 0..3
    const float w10 = W1[h], w11 = W1[128 + h], w12 = W1[256 + h];
    const float b1h = b1[h];
    __syncthreads();   // S1

    // ---- layer 1 -> amix
    float a2st[5];
    int nl[5], nv = 0;
    for (int s = 0; s < 5; ++s){ int n = q + 4*s; if (n < NNODE) nl[nv++] = n; }
    for (int s = 0; s < nv; ++s){
        int n = nl[s];
        for (int bl = 0; bl < 16; ++bl){
            float4 p1 = *(const float4*)&ps4[0][bl][n][0];
            float4 p2 = *(const float4*)&ps4[1][bl][n][0];
            float a1 = p1.x*w10 + p1.y*w11 + p1.z*w12;
            float a2 = p2.x*w10 + p2.y*w11 + p2.z*w12;
            if (bc == 0 && bl == 0){
                araw[n*128 + h] = a1;     // raw, pre-bias (layer-1 agg input)
                a2st[s] = a2;
            } else {
                float r1 = fmaxf(a1 + b1h, 0.f);
                float r2 = fmaxf(a2 + b1h, 0.f);
                Abuf[n*16 + bl][h] = f2b(0.5f*(r1 + r2));
            }
        }
    }
    __syncthreads();   // S2
    if (bc == 0){      // layer-1 aggregation for b=0, then relu
        for (int s = 0; s < nv; ++s){
            int n = nl[s]; float a = 0.f;
            #pragma unroll
            for (int j = 0; j < NNODE; ++j) a += As[n*17 + j] * araw[j*128 + h];
            araw2[n*128 + h] = fmaxf(a + b1h, 0.f);
        }
    }
    __syncthreads();   // S3
    if (bc == 0){      // layer-2 agg (commuted before W2): amix = 0.5*(A@r1 + r2)
        for (int s = 0; s < nv; ++s){
            int n = nl[s]; float a = 0.f;
            #pragma unroll
            for (int j = 0; j < NNODE; ++j) a += As[n*17 + j] * araw2[j*128 + h];
            float r2 = fmaxf(a2st[s] + b1h, 0.f);
            Abuf[n*16 + 0][h] = f2b(0.5f*(a + r2));
        }
    }
    __syncthreads();   // S4

    // ---- MFMA: feats[272 rows][128] = Abuf @ BsmT^T + b2
    const int w = tid >> 6, l = tid & 63;
    const int l15 = l & 15, q8 = (l >> 4) * 8, q4 = (l >> 4) * 4;
    float bias[8];
    #pragma unroll
    for (int nt = 0; nt < 8; ++nt) bias[nt] = b2[nt*16 + l15];

    bf16x8 Bf[4][8];
    #pragma unroll
    for (int kc = 0; kc < 4; ++kc)
        #pragma unroll
        for (int nt = 0; nt < 8; ++nt)
            Bf[kc][nt] = *(const bf16x8*)&BsmT[nt*16 + l15][kc*32 + q8];

    u16t* Cb = (u16t*)feats;
    for (int mt = w; mt < NNODE; mt += 8){
        f32x4 acc[8];
        #pragma unroll
        for (int nt = 0; nt < 8; ++nt) acc[nt] = (f32x4){0.f,0.f,0.f,0.f};
        #pragma unroll
        for (int kc = 0; kc < 4; ++kc){
            bf16x8 a = *(const bf16x8*)&Abuf[mt*16 + l15][kc*32 + q8];
            #pragma unroll
            for (int nt = 0; nt < 8; ++nt)
                acc[nt] = __builtin_amdgcn_mfma_f32_16x16x32_bf16(a, Bf[kc][nt], acc[nt], 0,0,0);
        }
        #pragma unroll
        for (int nt = 0; nt < 8; ++nt)
            #pragma unroll
            for (int r = 0; r < 4; ++r){
                size_t row = (size_t)(blk*16 + q4 + r) * NNODE + mt;  // (t*128+b)*17+n
                Cb[row*128 + nt*16 + l15] = f2b(acc[nt][r] + bias[nt]);
            }
    }
}

// ------------------------------------------------- pre_f GEMM (R2, validated)
__global__ __launch_bounds__(256) void k_gemm_mfma(
    const __hip_bfloat16* __restrict__ A, const float* __restrict__ Bw,
    const float* __restrict__ bi1, const float* __restrict__ bi2,
    __hip_bfloat16* __restrict__ C)
{
    __shared__ u16t Asm[128][32];
    __shared__ u16t Bsm[128][32];
    const int tid = threadIdx.x;
    const int w = tid >> 6;
    const int l = tid & 63;
    const size_t m0 = (size_t)blockIdx.x * 128;
    const int n0 = blockIdx.y * 128;
    const int mw = (w >> 1) * 64;
    const int nw = (w & 1) * 64;

    f32x4 acc[4][4];
    #pragma unroll
    for (int s = 0; s < 4; ++s)
        #pragma unroll
        for (int t_ = 0; t_ < 4; ++t_)
            acc[s][t_] = (f32x4){0.f, 0.f, 0.f, 0.f};

    const u16t* Ab = (const u16t*)A;
    const int arow = w*32 + (l>>2);
    const int akoff = (l&3)*8;
    const int brow = w*32 + (l>>1);
    const int bko  = (l&1)*16;
    const int fr = l & 15, fq = (l >> 4) * 8;

    for (int kt = 0; kt < DD; kt += 32){
        gload16(Ab + (m0 + arow)*DD + kt + akoff,      &Asm[arow][akoff]);
        gload16(Ab + (m0 + arow + 16)*DD + kt + akoff, &Asm[arow+16][akoff]);
        const float* bp = Bw + (size_t)(n0 + brow)*DD + kt + bko;
        float4 f0 = *(const float4*)bp;
        float4 f1 = *(const float4*)(bp+4);
        float4 f2 = *(const float4*)(bp+8);
        float4 f3 = *(const float4*)(bp+12);
        uint4 o0, o1;
        o0.x = pack2(f0.x,f0.y); o0.y = pack2(f0.z,f0.w);
        o0.z = pack2(f1.x,f1.y); o0.w = pack2(f1.z,f1.w);
        o1.x = pack2(f2.x,f2.y); o1.y = pack2(f2.z,f2.w);
        o1.z = pack2(f3.x,f3.y); o1.w = pack2(f3.z,f3.w);
        *(uint4*)&Bsm[brow][bko]   = o0;
        *(uint4*)&Bsm[brow][bko+8] = o1;
        __syncthreads();

        bf16x8 af[4], bf[4];
        #pragma unroll
        for (int s = 0; s < 4; ++s) af[s] = *(const bf16x8*)&Asm[mw + s*16 + fr][fq];
        #pragma unroll
        for (int t_ = 0; t_ < 4; ++t_) bf[t_] = *(const bf16x8*)&Bsm[nw + t_*16 + fr][fq];
        #pragma unroll
        for (int s = 0; s < 4; ++s)
            #pragma unroll
            for (int t_ = 0; t_ < 4; ++t_)
                acc[s][t_] = __builtin_amdgcn_mfma_f32_16x16x32_bf16(af[s], bf[t_], acc[s][t_], 0, 0, 0);
        __syncthreads();
    }

    const int cr = (l >> 4) * 4;
    const int cc = l & 15;
    u16t* Cb = (u16t*)C;
    #pragma unroll
    for (int t_ = 0; t_ < 4; ++t_){
        int col = n0 + nw + t_*16 + cc;
        float bias = bi1[col] + bi2[col];
        #pragma unroll
        for (int s = 0; s < 4; ++s)
            #pragma unroll
            for (int r = 0; r < 4; ++r){
                size_t row = m0 + mw + s*16 + cr + r;
                Cb[row*G4 + col] = f2b(acc[s][t_][r] + bias);
            }
    }
}

// --------------------- backward LSTM: one step from zero state (unchanged)
__global__ __launch_bounds__(256) void k_lstm_b(
    const __hip_bfloat16* __restrict__ feats255,
    const float* __restrict__ Wih_b,
    const float* __restrict__ bih_b, const float* __restrict__ bhh_b,
    float* __restrict__ h_b)
{
    __shared__ float fs[DD];
    const int tid = threadIdx.x;
    const int b = blockIdx.x;
    const unsigned* fbu = (const unsigned*)(feats255 + (size_t)b * DD);
    for (int i = tid; i < DD/2; i += 256){
        unsigned u = fbu[i];
        fs[2*i] = lo2f(u); fs[2*i+1] = hi2f(u);
    }
    __syncthreads();

    const int w = tid >> 6, lane = tid & 63;
    const int j = blockIdx.y * 4 + w;
    const float* Wi = Wih_b + (size_t)j * DD;
    const float* Wg = Wih_b + (size_t)(512 + j) * DD;
    const float* Wo = Wih_b + (size_t)(768 + j) * DD;
    float si = 0.f, sg = 0.f, so = 0.f;
    #pragma unroll 2
    for (int i = 0; i < 34; ++i){
        int k = lane + i*64;
        float f = fs[k];
        si += f * Wi[k]; sg += f * Wg[k]; so += f * Wo[k];
    }
    #pragma unroll
    for (int off = 32; off > 0; off >>= 1){
        si += __shfl_down(si, off);
        sg += __shfl_down(sg, off);
        so += __shfl_down(so, off);
    }
    if (lane == 0){
        float zi = si + bih_b[j]       + bhh_b[j];
        float zg = sg + bih_b[512 + j] + bhh_b[512 + j];
        float zo = so + bih_b[768 + j] + bhh_b[768 + j];
        float c = sigm(zi) * tanhf(zg);
        h_b[(size_t)b*LHID + j] = sigm(zo) * tanhf(c);
    }
}

// ------------------------- forward LSTM: MFMA recurrence, 8 WGs x 16 samples
// wave w owns cols [w*128, w*128+128). B streamed from WTfrag (L2), double-buf.
// h kept as bf16 hi+lo (2 MFMAs) for ~fp32 accuracy; c fp32 in regs.
__global__ __launch_bounds__(512) void k_lstm_f2(
    const __hip_bfloat16* __restrict__ pre,     // (256,128,1024) bf16
    const __hip_bfloat16* __restrict__ WTfrag,  // packed fragments
    float* __restrict__ hout)                   // (128,256)
{
    __shared__ u16t  hAhi[16][264];   // rows = sample, cols = k (pad 8)
    __shared__ u16t  hAlo[16][264];
    __shared__ float zb[16][1032];    // z, padded

    const int tid = threadIdx.x;
    const int s0 = blockIdx.x * 16;
    const int w = tid >> 6, l = tid & 63;
    const int l15 = l & 15, q8 = (l >> 4) * 8, q4 = (l >> 4) * 4;
    const int j = tid & 255, sp = tid >> 8;
    const u16t* preb = (const u16t*)pre;
    const u16t* wtf  = (const u16t*)WTfrag;

    for (int idx = tid; idx < 16*264; idx += 512){
        ((u16t*)hAhi)[idx] = 0; ((u16t*)hAlo)[idx] = 0;
    }
    float creg[8], hreg[8];
    #pragma unroll
    for (int si = 0; si < 8; ++si){ creg[si] = 0.f; hreg[si] = 0.f; }
    __syncthreads();

    for (int t = 0; t < TT; ++t){
        // prefetch pre for this step (consumed after the barrier)
        u16t prv[32];
        #pragma unroll
        for (int si = 0; si < 8; ++si){
            size_t base = ((size_t)t*BB + s0 + sp*8 + si) * G4 + j;
            #pragma unroll
            for (int g = 0; g < 4; ++g) prv[si*4 + g] = preb[base + g*256];
        }

        // MFMA: z[16][128 cols of this wave] = h @ Whh^T, K=256
        f32x4 acc[8];
        #pragma unroll
        for (int nt = 0; nt < 8; ++nt) acc[nt] = (f32x4){0.f,0.f,0.f,0.f};
        bf16x8 Bb[2][8];
        #pragma unroll
        for (int nt = 0; nt < 8; ++nt)
            Bb[0][nt] = *(const bf16x8*)(wtf + (((size_t)(w*64 + nt))<<9) + (l<<3));
        #pragma unroll
        for (int kc = 0; kc < 8; ++kc){
            const int cur = kc & 1, nxt = cur ^ 1;
            if (kc < 7){
                #pragma unroll
                for (int nt = 0; nt < 8; ++nt)
                    Bb[nxt][nt] = *(const bf16x8*)(wtf + (((size_t)(w*64 + (kc+1)*8 + nt))<<9) + (l<<3));
            }
            bf16x8 ah = *(const bf16x8*)&hAhi[l15][kc*32 + q8];
            bf16x8 al = *(const bf16x8*)&hAlo[l15][kc*32 + q8];
            #pragma unroll
            for (int nt = 0; nt < 8; ++nt)
                acc[nt] = __builtin_amdgcn_mfma_f32_16x16x32_bf16(ah, Bb[cur][nt], acc[nt], 0,0,0);
            #pragma unroll
            for (int nt = 0; nt < 8; ++nt)
                acc[nt] = __builtin_amdgcn_mfma_f32_16x16x32_bf16(al, Bb[cur][nt], acc[nt], 0,0,0);
        }
        #pragma unroll
        for (int nt = 0; nt < 8; ++nt)
            #pragma unroll
            for (int r = 0; r < 4; ++r)
                zb[q4 + r][w*128 + nt*16 + l15] = acc[nt][r];
        __syncthreads();

        // gates + state update; write h (bf16 hi/lo) for next step
        #pragma unroll
        for (int si = 0; si < 8; ++si){
            int s = sp*8 + si;
            float zi = zb[s][j]       + b2f(prv[si*4+0]);
            float zf = zb[s][256 + j] + b2f(prv[si*4+1]);
            float zg = zb[s][512 + j] + b2f(prv[si*4+2]);
            float zo = zb[s][768 + j] + b2f(prv[si*4+3]);
            float c = sigm(zf)*creg[si] + sigm(zi)*tanhf(zg);
            creg[si] = c;
            float hh = sigm(zo)*tanhf(c);
            hreg[si] = hh;
            u16t hb = f2b(hh);
            hAhi[s][j] = hb;
            hAlo[s][j] = f2b(hh - b2f(hb));
        }
        __syncthreads();
    }
    #pragma unroll
    for (int si = 0; si < 8; ++si)
        hout[(size_t)(s0 + sp*8 + si)*LHID + j] = hreg[si];
}

// ----------------------------------------------------- head (unchanged)
__global__ __launch_bounds__(256) void k_head(
    const float* __restrict__ h_f, const float* __restrict__ h_b,
    const float* __restrict__ Wc, const float* __restrict__ bc,
    float* __restrict__ out)
{
    __shared__ float pool[512];
    const int b = blockIdx.x, tid = threadIdx.x;
    float p0 = fmaxf(h_f[(size_t)b*LHID + tid], 0.f);
    float p1 = fmaxf(h_b[(size_t)b*LHID + tid], 0.f);
    pool[tid] = p0; pool[256 + tid] = p1;
    out[(size_t)b*512 + tid]       = p0;
    out[(size_t)b*512 + 256 + tid] = p1;
    __syncthreads();
    for (int n = tid; n < NCLS; n += 256){
        float a = bc[n];
        const float* ww = Wc + (size_t)n * 512;
        #pragma unroll 4
        for (int k = 0; k < 512; k += 4){
            float4 wv = *(const float4*)(ww + k);
            a += pool[k]*wv.x + pool[k+1]*wv.y + pool[k+2]*wv.z + pool[k+3]*wv.w;
        }
        out[(size_t)BB*512 + (size_t)b*NCLS + n] = a;
    }
}

// ---------------------------------------------------------------------------
extern "C" void kernel_launch(void* const* d_in, const int* in_sizes, int n_in,
                              void* d_out, int out_size, void* d_ws, size_t ws_size,
                              hipStream_t stream) {
    const float* pose1 = (const float*)d_in[0];
    const float* pose2 = (const float*)d_in[1];
    const float* W1    = (const float*)d_in[2];
    const float* b1    = (const float*)d_in[3];
    const float* W2    = (const float*)d_in[4];
    const float* b2    = (const float*)d_in[5];
    const float* Wih_f = (const float*)d_in[6];
    const float* Whh_f = (const float*)d_in[7];
    const float* bih_f = (const float*)d_in[8];
    const float* bhh_f = (const float*)d_in[9];
    const float* Wih_b = (const float*)d_in[10];
    const float* bih_b = (const float*)d_in[12];
    const float* bhh_b = (const float*)d_in[13];
    const float* Wc    = (const float*)d_in[14];
    const float* bc    = (const float*)d_in[15];
    (void)in_sizes; (void)n_in; (void)out_size; (void)ws_size;
    float* out = (float*)d_out;
    char* ws = (char*)d_ws;

    // workspace layout (<= 211,812,352 bytes, same footprint as R1/R2)
    __hip_bfloat16* WTfrag = (__hip_bfloat16*)(ws + 0);           // 524,288
    __hip_bfloat16* W2Tb   = (__hip_bfloat16*)(ws + 524288);      //  32,768
    float*          h_b    = (float*)(ws + 557056);               // 131,072
    float*          h_f    = (float*)(ws + 688128);               // 131,072
    __hip_bfloat16* feats  = (__hip_bfloat16*)(ws + 2097152);     // 142,606,336
    __hip_bfloat16* pre_f  = (__hip_bfloat16*)(ws + 144703488);   //  67,108,864

    k_w2t     <<<64, 256, 0, stream>>>(W2, W2Tb);
    k_wfrag   <<<128, 256, 0, stream>>>(Whh_f, WTfrag);
    k_gcnfused<<<2048, 512, 0, stream>>>(pose1, pose2, W1, b1, b2, W2Tb, feats);
    k_gemm_mfma<<<dim3(256, 8), 256, 0, stream>>>(feats, Wih_f, bih_f, bhh_f, pre_f);
    k_lstm_b  <<<dim3(128, 64), 256, 0, stream>>>(feats + (size_t)255*BB*DD, Wih_b, bih_b, bhh_b, h_b);
    k_lstm_f2 <<<8, 512, 0, stream>>>(pre_f, WTfrag, h_f);
    k_head    <<<128, 256, 0, stream>>>(h_f, h_b, Wc, bc, out);
}

// Round 4
// 2923.454 us; speedup vs baseline: 2.2802x; 1.1366x over previous
//
#include <hip/hip_runtime.h>
#include <hip/hip_bf16.h>

// ---------------------------------------------------------------------------
// PoseFeatureNet R4:
//  - k_lstm_f3: register-gate MFMA recurrence. Wave owns 32 j-cols x 4 gates,
//    z stays in acc regs (no zb LDS round trip), pre_f permuted so each lane
//    reads its gate pack as uint4. h hi/lo bf16 double-buffered in LDS,
//    ONE barrier/step. Whh: 2 kc resident in VGPR + 6 streamed from L2.
//    Gates via __expf/__fdividef (v_exp/v_rcp).
//  - k_gemm_mfma: epilogue writes pre2 in the permuted lane layout.
//  - k_gcnfused / k_lstm_b / k_head unchanged (validated R3).
// ---------------------------------------------------------------------------

#define TT 256
#define BB 128
#define NNODE 17
#define DD 2176    // 17*128
#define LHID 256
#define G4 1024    // 4*LHID
#define NCLS 625

typedef unsigned short u16t;

__device__ __constant__ int ESRC[19] = {15,13,16,14,11,5,6,5,5,6,7,8,1,0,0,1,2,3,4};
__device__ __constant__ int EDST[19] = {13,11,14,12,12,11,12,6,7,8,9,10,2,1,2,3,4,5,6};
__device__ __constant__ float DEGF[17] = {1,2,3,2,2,2,3,2,2,2,2,3,4,2,2,1,1};

__device__ inline float lo2f(unsigned u){ union{unsigned x; float f;} c; c.x = u << 16; return c.f; }
__device__ inline float hi2f(unsigned u){ union{unsigned x; float f;} c; c.x = u & 0xffff0000u; return c.f; }
__device__ inline u16t f2b(float f){
    __hip_bfloat16 h = __float2bfloat16(f);
    u16t s; __builtin_memcpy(&s, &h, 2); return s;
}
__device__ inline float b2f(u16t s){ union{unsigned x; float f;} c; c.x = ((unsigned)s) << 16; return c.f; }
__device__ inline unsigned pack2(float a, float b){
    return (unsigned)f2b(a) | ((unsigned)f2b(b) << 16);
}
__device__ inline float fsig(float x){ return __fdividef(1.f, 1.f + __expf(-x)); }
__device__ inline float ftanh(float x){ float e = __expf(2.f*x); return 1.f - __fdividef(2.f, e + 1.f); }
__device__ inline float sigm(float x){ return 1.f / (1.f + expf(-x)); }

typedef __attribute__((ext_vector_type(8))) short bf16x8;
typedef __attribute__((ext_vector_type(4))) float f32x4;

__device__ inline void gload16(const void* g, void* l){
    __builtin_amdgcn_global_load_lds(
        (const __attribute__((address_space(1))) void*)g,
        (__attribute__((address_space(3))) void*)l, 16, 0, 0);
}

// --------------------------------------------- W2 -> bf16 transposed [n][k]
__global__ void k_w2t(const float* __restrict__ W2, __hip_bfloat16* __restrict__ W2Tb){
    int g = blockIdx.x * 256 + threadIdx.x;   // 16384
    int k = g >> 7, n = g & 127;
    W2Tb[n * 128 + k] = __float2bfloat16(W2[g]);
}

// ------------------- Whh -> bf16 fragments, R4 packing
// frag f = (w*8 + kc)*8 + nt  (w:8 waves, kc:8 k-chunks, nt = gate*2 + jj5)
// lane l holds B[k = kc*32 + (l>>4)*8 + j][col = (nt>>1)*256 + w*32 + (nt&1)*16 + (l&15)]
__global__ void k_wfrag(const float* __restrict__ Whh, __hip_bfloat16* __restrict__ WTfrag){
    int g = blockIdx.x * 256 + threadIdx.x;   // 32768
    int f = g >> 6, lane = g & 63;
    int w = f >> 6, kc = (f >> 3) & 7, nt = f & 7;
    int col = (nt >> 1)*256 + w*32 + (nt & 1)*16 + (lane & 15);
    int k0  = kc*32 + (lane >> 4)*8;
    const float* src = Whh + (size_t)col * 256 + k0;
    float4 f0 = *(const float4*)src;
    float4 f1 = *(const float4*)(src + 4);
    uint4 o;
    o.x = pack2(f0.x, f0.y); o.y = pack2(f0.z, f0.w);
    o.z = pack2(f1.x, f1.y); o.w = pack2(f1.z, f1.w);
    *(uint4*)((char*)WTfrag + (size_t)g * 16) = o;
}

// ------------------------------------------------------------ fused GCN block
__global__ __launch_bounds__(512) void k_gcnfused(
    const float* __restrict__ pose1, const float* __restrict__ pose2,
    const float* __restrict__ W1, const float* __restrict__ b1,
    const float* __restrict__ b2, const __hip_bfloat16* __restrict__ W2Tb,
    __hip_bfloat16* __restrict__ feats)
{
    __shared__ u16t  Abuf[272][136];
    __shared__ u16t  BsmT[128][136];
    __shared__ float ps4[2][16][17][4];
    __shared__ float araw[17*128];
    __shared__ float araw2[17*128];
    __shared__ float As[289];

    const int tid = threadIdx.x;
    const int blk = blockIdx.x;
    const int t   = blk >> 3;
    const int bc  = blk & 7;

    for (int idx = tid; idx < 1632; idx += 512){
        int p_ = idx >= 816 ? 1 : 0;
        int r  = idx - p_ * 816;
        int bl = r / 51, i = r - bl * 51;
        int n = i / 3, c = i - n * 3;
        const float* src = p_ ? pose2 : pose1;
        ps4[p_][bl][n][c] = src[(size_t)((bc*16 + bl) * TT + t) * 51 + i];
    }
    {
        const uint4* src = (const uint4*)W2Tb;
        for (int r = 0; r < 2; ++r){
            int f0 = (tid + r * 512) * 16;
            int n = f0 >> 7, k0 = f0 & 127;
            uint4 v0 = src[(tid + r*512)*2 + 0];
            uint4 v1 = src[(tid + r*512)*2 + 1];
            *(uint4*)&BsmT[n][k0]     = v0;
            *(uint4*)&BsmT[n][k0 + 8] = v1;
        }
    }
    if (bc == 0 && tid < 289){
        int i = tid / 17, j = tid - (tid/17)*17;
        float a = (i == j) ? 1.0f / DEGF[i] : 0.0f;
        for (int e = 0; e < 19; ++e)
            if (EDST[e] == i && ESRC[e] == j)
                a += 1.0f / sqrtf(DEGF[i] * DEGF[j]);
        As[tid] = a;
    }

    const int h = tid & 127;
    const int q = tid >> 7;
    const float w10 = W1[h], w11 = W1[128 + h], w12 = W1[256 + h];
    const float b1h = b1[h];
    __syncthreads();

    float a2st[5];
    int nl[5], nv = 0;
    for (int s = 0; s < 5; ++s){ int n = q + 4*s; if (n < NNODE) nl[nv++] = n; }
    for (int s = 0; s < nv; ++s){
        int n = nl[s];
        for (int bl = 0; bl < 16; ++bl){
            float4 p1 = *(const float4*)&ps4[0][bl][n][0];
            float4 p2 = *(const float4*)&ps4[1][bl][n][0];
            float a1 = p1.x*w10 + p1.y*w11 + p1.z*w12;
            float a2 = p2.x*w10 + p2.y*w11 + p2.z*w12;
            if (bc == 0 && bl == 0){
                araw[n*128 + h] = a1;
                a2st[s] = a2;
            } else {
                float r1 = fmaxf(a1 + b1h, 0.f);
                float r2 = fmaxf(a2 + b1h, 0.f);
                Abuf[n*16 + bl][h] = f2b(0.5f*(r1 + r2));
            }
        }
    }
    __syncthreads();
    if (bc == 0){
        for (int s = 0; s < nv; ++s){
            int n = nl[s]; float a = 0.f;
            #pragma unroll
            for (int j = 0; j < NNODE; ++j) a += As[n*17 + j] * araw[j*128 + h];
            araw2[n*128 + h] = fmaxf(a + b1h, 0.f);
        }
    }
    __syncthreads();
    if (bc == 0){
        for (int s = 0; s < nv; ++s){
            int n = nl[s]; float a = 0.f;
            #pragma unroll
            for (int j = 0; j < NNODE; ++j) a += As[n*17 + j] * araw2[j*128 + h];
            float r2 = fmaxf(a2st[s] + b1h, 0.f);
            Abuf[n*16 + 0][h] = f2b(0.5f*(a + r2));
        }
    }
    __syncthreads();

    const int w = tid >> 6, l = tid & 63;
    const int l15 = l & 15, q8 = (l >> 4) * 8, q4 = (l >> 4) * 4;
    float bias[8];
    #pragma unroll
    for (int nt = 0; nt < 8; ++nt) bias[nt] = b2[nt*16 + l15];

    bf16x8 Bf[4][8];
    #pragma unroll
    for (int kc = 0; kc < 4; ++kc)
        #pragma unroll
        for (int nt = 0; nt < 8; ++nt)
            Bf[kc][nt] = *(const bf16x8*)&BsmT[nt*16 + l15][kc*32 + q8];

    u16t* Cb = (u16t*)feats;
    for (int mt = w; mt < NNODE; mt += 8){
        f32x4 acc[8];
        #pragma unroll
        for (int nt = 0; nt < 8; ++nt) acc[nt] = (f32x4){0.f,0.f,0.f,0.f};
        #pragma unroll
        for (int kc = 0; kc < 4; ++kc){
            bf16x8 a = *(const bf16x8*)&Abuf[mt*16 + l15][kc*32 + q8];
            #pragma unroll
            for (int nt = 0; nt < 8; ++nt)
                acc[nt] = __builtin_amdgcn_mfma_f32_16x16x32_bf16(a, Bf[kc][nt], acc[nt], 0,0,0);
        }
        #pragma unroll
        for (int nt = 0; nt < 8; ++nt)
            #pragma unroll
            for (int r = 0; r < 4; ++r){
                size_t row = (size_t)(blk*16 + q4 + r) * NNODE + mt;
                Cb[row*128 + nt*16 + l15] = f2b(acc[nt][r] + bias[nt]);
            }
    }
}

// ------------------------------------------------- pre_f GEMM: bf16 MFMA
// Epilogue writes permuted pre2 layout:
// idx = t*131072 + (b>>4)*16384 + w*2048 + q*512 + r*128 + l15*8 + nt
// where w=(col&255)>>5, nt=(col>>8)*2+((col>>4)&1), l15=col&15,
//       q=((b&15)>>2), r=b&3.
__global__ __launch_bounds__(256) void k_gemm_mfma(
    const __hip_bfloat16* __restrict__ A, const float* __restrict__ Bw,
    const float* __restrict__ bi1, const float* __restrict__ bi2,
    u16t* __restrict__ pre2)
{
    __shared__ u16t Asm[128][32];
    __shared__ u16t Bsm[128][32];
    const int tid = threadIdx.x;
    const int w = tid >> 6;
    const int l = tid & 63;
    const size_t m0 = (size_t)blockIdx.x * 128;
    const int n0 = blockIdx.y * 128;
    const int mw = (w >> 1) * 64;
    const int nw = (w & 1) * 64;

    f32x4 acc[4][4];
    #pragma unroll
    for (int s = 0; s < 4; ++s)
        #pragma unroll
        for (int t_ = 0; t_ < 4; ++t_)
            acc[s][t_] = (f32x4){0.f, 0.f, 0.f, 0.f};

    const u16t* Ab = (const u16t*)A;
    const int arow = w*32 + (l>>2);
    const int akoff = (l&3)*8;
    const int brow = w*32 + (l>>1);
    const int bko  = (l&1)*16;
    const int fr = l & 15, fq = (l >> 4) * 8;

    for (int kt = 0; kt < DD; kt += 32){
        gload16(Ab + (m0 + arow)*DD + kt + akoff,      &Asm[arow][akoff]);
        gload16(Ab + (m0 + arow + 16)*DD + kt + akoff, &Asm[arow+16][akoff]);
        const float* bp = Bw + (size_t)(n0 + brow)*DD + kt + bko;
        float4 f0 = *(const float4*)bp;
        float4 f1 = *(const float4*)(bp+4);
        float4 f2 = *(const float4*)(bp+8);
        float4 f3 = *(const float4*)(bp+12);
        uint4 o0, o1;
        o0.x = pack2(f0.x,f0.y); o0.y = pack2(f0.z,f0.w);
        o0.z = pack2(f1.x,f1.y); o0.w = pack2(f1.z,f1.w);
        o1.x = pack2(f2.x,f2.y); o1.y = pack2(f2.z,f2.w);
        o1.z = pack2(f3.x,f3.y); o1.w = pack2(f3.z,f3.w);
        *(uint4*)&Bsm[brow][bko]   = o0;
        *(uint4*)&Bsm[brow][bko+8] = o1;
        __syncthreads();

        bf16x8 af[4], bf[4];
        #pragma unroll
        for (int s = 0; s < 4; ++s) af[s] = *(const bf16x8*)&Asm[mw + s*16 + fr][fq];
        #pragma unroll
        for (int t_ = 0; t_ < 4; ++t_) bf[t_] = *(const bf16x8*)&Bsm[nw + t_*16 + fr][fq];
        #pragma unroll
        for (int s = 0; s < 4; ++s)
            #pragma unroll
            for (int t_ = 0; t_ < 4; ++t_)
                acc[s][t_] = __builtin_amdgcn_mfma_f32_16x16x32_bf16(af[s], bf[t_], acc[s][t_], 0, 0, 0);
        __syncthreads();
    }

    const int cr = (l >> 4) * 4;
    const int cc = l & 15;
    const int tIdx = blockIdx.x;   // rows are t-major: row = t*128 + b
    #pragma unroll
    for (int t_ = 0; t_ < 4; ++t_){
        int col = n0 + nw + t_*16 + cc;
        float bias = bi1[col] + bi2[col];
        int wj  = (col & 255) >> 5;
        int nt  = (col >> 8)*2 + ((col >> 4) & 1);
        int l15 = col & 15;
        size_t cbase = (size_t)tIdx*131072 + (size_t)wj*2048 + l15*8 + nt;
        #pragma unroll
        for (int s = 0; s < 4; ++s)
            #pragma unroll
            for (int r = 0; r < 4; ++r){
                int b = mw + s*16 + cr + r;
                pre2[cbase + (size_t)(b>>4)*16384 + ((b&15)>>2)*512 + (b&3)*128]
                    = f2b(acc[s][t_][r] + bias);
            }
    }
}

// --------------------- backward LSTM: one step from zero state (unchanged)
__global__ __launch_bounds__(256) void k_lstm_b(
    const __hip_bfloat16* __restrict__ feats255,
    const float* __restrict__ Wih_b,
    const float* __restrict__ bih_b, const float* __restrict__ bhh_b,
    float* __restrict__ h_b)
{
    __shared__ float fs[DD];
    const int tid = threadIdx.x;
    const int b = blockIdx.x;
    const unsigned* fbu = (const unsigned*)(feats255 + (size_t)b * DD);
    for (int i = tid; i < DD/2; i += 256){
        unsigned u = fbu[i];
        fs[2*i] = lo2f(u); fs[2*i+1] = hi2f(u);
    }
    __syncthreads();

    const int w = tid >> 6, lane = tid & 63;
    const int j = blockIdx.y * 4 + w;
    const float* Wi = Wih_b + (size_t)j * DD;
    const float* Wg = Wih_b + (size_t)(512 + j) * DD;
    const float* Wo = Wih_b + (size_t)(768 + j) * DD;
    float si = 0.f, sg = 0.f, so = 0.f;
    #pragma unroll 2
    for (int i = 0; i < 34; ++i){
        int k = lane + i*64;
        float f = fs[k];
        si += f * Wi[k]; sg += f * Wg[k]; so += f * Wo[k];
    }
    #pragma unroll
    for (int off = 32; off > 0; off >>= 1){
        si += __shfl_down(si, off);
        sg += __shfl_down(sg, off);
        so += __shfl_down(so, off);
    }
    if (lane == 0){
        float zi = si + bih_b[j]       + bhh_b[j];
        float zg = sg + bih_b[512 + j] + bhh_b[512 + j];
        float zo = so + bih_b[768 + j] + bhh_b[768 + j];
        float c = sigm(zi) * tanhf(zg);
        h_b[(size_t)b*LHID + j] = sigm(zo) * tanhf(c);
    }
}

// ------------------- forward LSTM R4: register-gate MFMA recurrence
// 8 WGs x 16 samples, 512 threads (8 waves). Wave w owns j in [w*32,w*32+32)
// for ALL 4 gates (nt = gate*2 + jj5). One barrier per step.
#define MSTEP(kc, Bp) { \
    bf16x8 ah = *(const bf16x8*)&hAhi[tb][l15][(kc)*32 + q8]; \
    bf16x8 al = *(const bf16x8*)&hAlo[tb][l15][(kc)*32 + q8]; \
    _Pragma("unroll") for (int nt = 0; nt < 8; ++nt){ \
        acc[nt] = __builtin_amdgcn_mfma_f32_16x16x32_bf16(ah, (Bp)[nt], acc[nt], 0,0,0); \
        acc[nt] = __builtin_amdgcn_mfma_f32_16x16x32_bf16(al, (Bp)[nt], acc[nt], 0,0,0); } }

#define LDF(dst, kc) { _Pragma("unroll") for (int nt = 0; nt < 8; ++nt) \
    (dst)[nt] = *(const bf16x8*)(wtf + ((((size_t)(w*8 + (kc)))*8 + nt)*64 + l)*8); }

__global__ __launch_bounds__(512) void k_lstm_f3(
    const u16t* __restrict__ pre2,            // permuted (see gemm epilogue)
    const __hip_bfloat16* __restrict__ WTfrag,
    float* __restrict__ hout)                 // (128,256)
{
    __shared__ u16t hAhi[2][16][264];
    __shared__ u16t hAlo[2][16][264];
    const int tid = threadIdx.x;
    const int w = tid >> 6, l = tid & 63;
    const int q = l >> 4, l15 = l & 15, q8 = q * 8;
    const int wg = blockIdx.x;
    const u16t* wtf = (const u16t*)WTfrag;

    for (int i = tid; i < 16*264; i += 512){
        ((u16t*)hAhi[0])[i] = 0; ((u16t*)hAlo[0])[i] = 0;
        ((u16t*)hAhi[1])[i] = 0; ((u16t*)hAlo[1])[i] = 0;
    }

    bf16x8 Bres[2][8];
    LDF(Bres[0], 0);
    LDF(Bres[1], 1);
    float cst[8];
    #pragma unroll
    for (int i = 0; i < 8; ++i) cst[i] = 0.f;
    // pre base (shorts): t*131072 + wg*16384 + w*2048 + q*512 + r*128 + l15*8 + nt
    const size_t pbase0 = (size_t)wg*16384 + (size_t)w*2048 + (size_t)q*512 + (size_t)l15*8;
    __syncthreads();

    #pragma unroll 1
    for (int t = 0; t < TT; ++t){
        const int tb = t & 1, bufn = tb ^ 1;
        // prefetch pre (one uint4 per sample-row r)
        union { uint4 v; u16t s[8]; } pr[4];
        {
            const u16t* pp = pre2 + (size_t)t*131072 + pbase0;
            #pragma unroll
            for (int r = 0; r < 4; ++r) pr[r].v = *(const uint4*)(pp + r*128);
        }
        bf16x8 Sa[8], Sb[8];
        LDF(Sa, 2); LDF(Sb, 3);

        f32x4 acc[8];
        #pragma unroll
        for (int nt = 0; nt < 8; ++nt) acc[nt] = (f32x4){0.f,0.f,0.f,0.f};

        MSTEP(0, Bres[0]);
        MSTEP(1, Bres[1]);
        MSTEP(2, Sa);  LDF(Sa, 4);
        MSTEP(3, Sb);  LDF(Sb, 5);
        MSTEP(4, Sa);  LDF(Sa, 6);
        MSTEP(5, Sb);  LDF(Sb, 7);
        MSTEP(6, Sa);
        MSTEP(7, Sb);

        // gates fully in registers
        #pragma unroll
        for (int jj5 = 0; jj5 < 2; ++jj5){
            const int j = w*32 + jj5*16 + l15;
            #pragma unroll
            for (int r = 0; r < 4; ++r){
                float zi = acc[0 + jj5][r] + b2f(pr[r].s[0 + jj5]);
                float zf = acc[2 + jj5][r] + b2f(pr[r].s[2 + jj5]);
                float zg = acc[4 + jj5][r] + b2f(pr[r].s[4 + jj5]);
                float zo = acc[6 + jj5][r] + b2f(pr[r].s[6 + jj5]);
                float cn = fsig(zf)*cst[jj5*4 + r] + fsig(zi)*ftanh(zg);
                cst[jj5*4 + r] = cn;
                float hh = fsig(zo)*ftanh(cn);
                const int s = q*4 + r;
                u16t hb = f2b(hh);
                hAhi[bufn][s][j] = hb;
                hAlo[bufn][s][j] = f2b(hh - b2f(hb));
                if (t == TT-1)
                    hout[((size_t)wg*16 + s)*LHID + j] = hh;
            }
        }
        __syncthreads();
    }
}

// ----------------------------------------------------- head (unchanged)
__global__ __launch_bounds__(256) void k_head(
    const float* __restrict__ h_f, const float* __restrict__ h_b,
    const float* __restrict__ Wc, const float* __restrict__ bc,
    float* __restrict__ out)
{
    __shared__ float pool[512];
    const int b = blockIdx.x, tid = threadIdx.x;
    float p0 = fmaxf(h_f[(size_t)b*LHID + tid], 0.f);
    float p1 = fmaxf(h_b[(size_t)b*LHID + tid], 0.f);
    pool[tid] = p0; pool[256 + tid] = p1;
    out[(size_t)b*512 + tid]       = p0;
    out[(size_t)b*512 + 256 + tid] = p1;
    __syncthreads();
    for (int n = tid; n < NCLS; n += 256){
        float a = bc[n];
        const float* ww = Wc + (size_t)n * 512;
        #pragma unroll 4
        for (int k = 0; k < 512; k += 4){
            float4 wv = *(const float4*)(ww + k);
            a += pool[k]*wv.x + pool[k+1]*wv.y + pool[k+2]*wv.z + pool[k+3]*wv.w;
        }
        out[(size_t)BB*512 + (size_t)b*NCLS + n] = a;
    }
}

// ---------------------------------------------------------------------------
extern "C" void kernel_launch(void* const* d_in, const int* in_sizes, int n_in,
                              void* d_out, int out_size, void* d_ws, size_t ws_size,
                              hipStream_t stream) {
    const float* pose1 = (const float*)d_in[0];
    const float* pose2 = (const float*)d_in[1];
    const float* W1    = (const float*)d_in[2];
    const float* b1    = (const float*)d_in[3];
    const float* W2    = (const float*)d_in[4];
    const float* b2    = (const float*)d_in[5];
    const float* Wih_f = (const float*)d_in[6];
    const float* Whh_f = (const float*)d_in[7];
    const float* bih_f = (const float*)d_in[8];
    const float* bhh_f = (const float*)d_in[9];
    const float* Wih_b = (const float*)d_in[10];
    const float* bih_b = (const float*)d_in[12];
    const float* bhh_b = (const float*)d_in[13];
    const float* Wc    = (const float*)d_in[14];
    const float* bc    = (const float*)d_in[15];
    (void)in_sizes; (void)n_in; (void)out_size; (void)ws_size;
    float* out = (float*)d_out;
    char* ws = (char*)d_ws;

    // workspace (same 211,812,352-byte footprint as R1-R3)
    __hip_bfloat16* WTfrag = (__hip_bfloat16*)(ws + 0);           // 524,288
    __hip_bfloat16* W2Tb   = (__hip_bfloat16*)(ws + 524288);      //  32,768
    float*          h_b    = (float*)(ws + 557056);               // 131,072
    float*          h_f    = (float*)(ws + 688128);               // 131,072
    __hip_bfloat16* feats  = (__hip_bfloat16*)(ws + 2097152);     // 142,606,336
    u16t*           pre2   = (u16t*)(ws + 144703488);             //  67,108,864

    k_w2t     <<<64, 256, 0, stream>>>(W2, W2Tb);
    k_wfrag   <<<128, 256, 0, stream>>>(Whh_f, WTfrag);
    k_gcnfused<<<2048, 512, 0, stream>>>(pose1, pose2, W1, b1, b2, W2Tb, feats);
    k_gemm_mfma<<<dim3(256, 8), 256, 0, stream>>>(feats, Wih_f, bih_f, bhh_f, pre2);
    k_lstm_b  <<<dim3(128, 64), 256, 0, stream>>>(feats + (size_t)255*BB*DD, Wih_b, bih_b, bhh_b, h_b);
    k_lstm_f3 <<<8, 512, 0, stream>>>(pre2, WTfrag, h_f);
    k_head    <<<128, 256, 0, stream>>>(h_f, h_b, Wc, bc, out);
}

// Round 5
// 2912.106 us; speedup vs baseline: 2.2891x; 1.0039x over previous
//
#include <hip/hip_runtime.h>
#include <hip/hip_bf16.h>

// ---------------------------------------------------------------------------
// PoseFeatureNet R5:
//  - k_lstm_f4: 1024 threads (16 waves, 4/SIMD). Wave owns 16 j x 4 gates
//    (nt=gate). Whh kc0-1 resident in VGPRs, kc2-7 streamed double-buffered
//    with cross-step prefetch. Register gates, one barrier/step.
//  - k_wfrag / k_gemm_mfma epilogue repacked for the new lane layout.
//  - k_gcnfused / k_lstm_b / k_head unchanged.
// ---------------------------------------------------------------------------

#define TT 256
#define BB 128
#define NNODE 17
#define DD 2176    // 17*128
#define LHID 256
#define G4 1024    // 4*LHID
#define NCLS 625

typedef unsigned short u16t;

__device__ __constant__ int ESRC[19] = {15,13,16,14,11,5,6,5,5,6,7,8,1,0,0,1,2,3,4};
__device__ __constant__ int EDST[19] = {13,11,14,12,12,11,12,6,7,8,9,10,2,1,2,3,4,5,6};
__device__ __constant__ float DEGF[17] = {1,2,3,2,2,2,3,2,2,2,2,3,4,2,2,1,1};

__device__ inline float lo2f(unsigned u){ union{unsigned x; float f;} c; c.x = u << 16; return c.f; }
__device__ inline float hi2f(unsigned u){ union{unsigned x; float f;} c; c.x = u & 0xffff0000u; return c.f; }
__device__ inline u16t f2b(float f){
    __hip_bfloat16 h = __float2bfloat16(f);
    u16t s; __builtin_memcpy(&s, &h, 2); return s;
}
__device__ inline float b2f(u16t s){ union{unsigned x; float f;} c; c.x = ((unsigned)s) << 16; return c.f; }
__device__ inline unsigned pack2(float a, float b){
    return (unsigned)f2b(a) | ((unsigned)f2b(b) << 16);
}
__device__ inline float fsig(float x){ return __fdividef(1.f, 1.f + __expf(-x)); }
__device__ inline float ftanh(float x){ float e = __expf(2.f*x); return 1.f - __fdividef(2.f, e + 1.f); }
__device__ inline float sigm(float x){ return 1.f / (1.f + expf(-x)); }

typedef __attribute__((ext_vector_type(8))) short bf16x8;
typedef __attribute__((ext_vector_type(4))) float f32x4;

__device__ inline void gload16(const void* g, void* l){
    __builtin_amdgcn_global_load_lds(
        (const __attribute__((address_space(1))) void*)g,
        (__attribute__((address_space(3))) void*)l, 16, 0, 0);
}

// --------------------------------------------- W2 -> bf16 transposed [n][k]
__global__ void k_w2t(const float* __restrict__ W2, __hip_bfloat16* __restrict__ W2Tb){
    int g = blockIdx.x * 256 + threadIdx.x;   // 16384
    int k = g >> 7, n = g & 127;
    W2Tb[n * 128 + k] = __float2bfloat16(W2[g]);
}

// ------------------- Whh -> bf16 fragments, R5 packing (16 waves, nt = gate)
// frag f = w*32 + kc*4 + nt  (w:16 waves, kc:8, nt:4 gates)
// lane l holds B[k = kc*32 + (l>>4)*8 ..+8][col = nt*256 + w*16 + (l&15)]
__global__ void k_wfrag(const float* __restrict__ Whh, __hip_bfloat16* __restrict__ WTfrag){
    int g = blockIdx.x * 256 + threadIdx.x;   // 32768
    int f = g >> 6, lane = g & 63;
    int w = f >> 5, kc = (f >> 2) & 7, nt = f & 3;
    int col = nt*256 + w*16 + (lane & 15);
    int k0  = kc*32 + (lane >> 4)*8;
    const float* src = Whh + (size_t)col * 256 + k0;
    float4 f0 = *(const float4*)src;
    float4 f1 = *(const float4*)(src + 4);
    uint4 o;
    o.x = pack2(f0.x, f0.y); o.y = pack2(f0.z, f0.w);
    o.z = pack2(f1.x, f1.y); o.w = pack2(f1.z, f1.w);
    *(uint4*)((char*)WTfrag + (size_t)g * 16) = o;
}

// ------------------------------------------------------------ fused GCN block
__global__ __launch_bounds__(512) void k_gcnfused(
    const float* __restrict__ pose1, const float* __restrict__ pose2,
    const float* __restrict__ W1, const float* __restrict__ b1,
    const float* __restrict__ b2, const __hip_bfloat16* __restrict__ W2Tb,
    __hip_bfloat16* __restrict__ feats)
{
    __shared__ u16t  Abuf[272][136];
    __shared__ u16t  BsmT[128][136];
    __shared__ float ps4[2][16][17][4];
    __shared__ float araw[17*128];
    __shared__ float araw2[17*128];
    __shared__ float As[289];

    const int tid = threadIdx.x;
    const int blk = blockIdx.x;
    const int t   = blk >> 3;
    const int bc  = blk & 7;

    for (int idx = tid; idx < 1632; idx += 512){
        int p_ = idx >= 816 ? 1 : 0;
        int r  = idx - p_ * 816;
        int bl = r / 51, i = r - bl * 51;
        int n = i / 3, c = i - n * 3;
        const float* src = p_ ? pose2 : pose1;
        ps4[p_][bl][n][c] = src[(size_t)((bc*16 + bl) * TT + t) * 51 + i];
    }
    {
        const uint4* src = (const uint4*)W2Tb;
        for (int r = 0; r < 2; ++r){
            int f0 = (tid + r * 512) * 16;
            int n = f0 >> 7, k0 = f0 & 127;
            uint4 v0 = src[(tid + r*512)*2 + 0];
            uint4 v1 = src[(tid + r*512)*2 + 1];
            *(uint4*)&BsmT[n][k0]     = v0;
            *(uint4*)&BsmT[n][k0 + 8] = v1;
        }
    }
    if (bc == 0 && tid < 289){
        int i = tid / 17, j = tid - (tid/17)*17;
        float a = (i == j) ? 1.0f / DEGF[i] : 0.0f;
        for (int e = 0; e < 19; ++e)
            if (EDST[e] == i && ESRC[e] == j)
                a += 1.0f / sqrtf(DEGF[i] * DEGF[j]);
        As[tid] = a;
    }

    const int h = tid & 127;
    const int q = tid >> 7;
    const float w10 = W1[h], w11 = W1[128 + h], w12 = W1[256 + h];
    const float b1h = b1[h];
    __syncthreads();

    float a2st[5];
    int nl[5], nv = 0;
    for (int s = 0; s < 5; ++s){ int n = q + 4*s; if (n < NNODE) nl[nv++] = n; }
    for (int s = 0; s < nv; ++s){
        int n = nl[s];
        for (int bl = 0; bl < 16; ++bl){
            float4 p1 = *(const float4*)&ps4[0][bl][n][0];
            float4 p2 = *(const float4*)&ps4[1][bl][n][0];
            float a1 = p1.x*w10 + p1.y*w11 + p1.z*w12;
            float a2 = p2.x*w10 + p2.y*w11 + p2.z*w12;
            if (bc == 0 && bl == 0){
                araw[n*128 + h] = a1;
                a2st[s] = a2;
            } else {
                float r1 = fmaxf(a1 + b1h, 0.f);
                float r2 = fmaxf(a2 + b1h, 0.f);
                Abuf[n*16 + bl][h] = f2b(0.5f*(r1 + r2));
            }
        }
    }
    __syncthreads();
    if (bc == 0){
        for (int s = 0; s < nv; ++s){
            int n = nl[s]; float a = 0.f;
            #pragma unroll
            for (int j = 0; j < NNODE; ++j) a += As[n*17 + j] * araw[j*128 + h];
            araw2[n*128 + h] = fmaxf(a + b1h, 0.f);
        }
    }
    __syncthreads();
    if (bc == 0){
        for (int s = 0; s < nv; ++s){
            int n = nl[s]; float a = 0.f;
            #pragma unroll
            for (int j = 0; j < NNODE; ++j) a += As[n*17 + j] * araw2[j*128 + h];
            float r2 = fmaxf(a2st[s] + b1h, 0.f);
            Abuf[n*16 + 0][h] = f2b(0.5f*(a + r2));
        }
    }
    __syncthreads();

    const int w = tid >> 6, l = tid & 63;
    const int l15 = l & 15, q8 = (l >> 4) * 8, q4 = (l >> 4) * 4;
    float bias[8];
    #pragma unroll
    for (int nt = 0; nt < 8; ++nt) bias[nt] = b2[nt*16 + l15];

    bf16x8 Bf[4][8];
    #pragma unroll
    for (int kc = 0; kc < 4; ++kc)
        #pragma unroll
        for (int nt = 0; nt < 8; ++nt)
            Bf[kc][nt] = *(const bf16x8*)&BsmT[nt*16 + l15][kc*32 + q8];

    u16t* Cb = (u16t*)feats;
    for (int mt = w; mt < NNODE; mt += 8){
        f32x4 acc[8];
        #pragma unroll
        for (int nt = 0; nt < 8; ++nt) acc[nt] = (f32x4){0.f,0.f,0.f,0.f};
        #pragma unroll
        for (int kc = 0; kc < 4; ++kc){
            bf16x8 a = *(const bf16x8*)&Abuf[mt*16 + l15][kc*32 + q8];
            #pragma unroll
            for (int nt = 0; nt < 8; ++nt)
                acc[nt] = __builtin_amdgcn_mfma_f32_16x16x32_bf16(a, Bf[kc][nt], acc[nt], 0,0,0);
        }
        #pragma unroll
        for (int nt = 0; nt < 8; ++nt)
            #pragma unroll
            for (int r = 0; r < 4; ++r){
                size_t row = (size_t)(blk*16 + q4 + r) * NNODE + mt;
                Cb[row*128 + nt*16 + l15] = f2b(acc[nt][r] + bias[nt]);
            }
    }
}

// ------------------------------------------------- pre_f GEMM: bf16 MFMA
// Epilogue writes pre2 in R5 permuted layout:
// off = t*131072 + (b>>4)*16384 + (j>>4)*1024 + ((b&15)>>2)*256 + (b&3)*64
//       + (j&15)*4 + gate      where col = gate*256 + j
__global__ __launch_bounds__(256) void k_gemm_mfma(
    const __hip_bfloat16* __restrict__ A, const float* __restrict__ Bw,
    const float* __restrict__ bi1, const float* __restrict__ bi2,
    u16t* __restrict__ pre2)
{
    __shared__ u16t Asm[128][32];
    __shared__ u16t Bsm[128][32];
    const int tid = threadIdx.x;
    const int w = tid >> 6;
    const int l = tid & 63;
    const size_t m0 = (size_t)blockIdx.x * 128;
    const int n0 = blockIdx.y * 128;
    const int mw = (w >> 1) * 64;
    const int nw = (w & 1) * 64;

    f32x4 acc[4][4];
    #pragma unroll
    for (int s = 0; s < 4; ++s)
        #pragma unroll
        for (int t_ = 0; t_ < 4; ++t_)
            acc[s][t_] = (f32x4){0.f, 0.f, 0.f, 0.f};

    const u16t* Ab = (const u16t*)A;
    const int arow = w*32 + (l>>2);
    const int akoff = (l&3)*8;
    const int brow = w*32 + (l>>1);
    const int bko  = (l&1)*16;
    const int fr = l & 15, fq = (l >> 4) * 8;

    for (int kt = 0; kt < DD; kt += 32){
        gload16(Ab + (m0 + arow)*DD + kt + akoff,      &Asm[arow][akoff]);
        gload16(Ab + (m0 + arow + 16)*DD + kt + akoff, &Asm[arow+16][akoff]);
        const float* bp = Bw + (size_t)(n0 + brow)*DD + kt + bko;
        float4 f0 = *(const float4*)bp;
        float4 f1 = *(const float4*)(bp+4);
        float4 f2 = *(const float4*)(bp+8);
        float4 f3 = *(const float4*)(bp+12);
        uint4 o0, o1;
        o0.x = pack2(f0.x,f0.y); o0.y = pack2(f0.z,f0.w);
        o0.z = pack2(f1.x,f1.y); o0.w = pack2(f1.z,f1.w);
        o1.x = pack2(f2.x,f2.y); o1.y = pack2(f2.z,f2.w);
        o1.z = pack2(f3.x,f3.y); o1.w = pack2(f3.z,f3.w);
        *(uint4*)&Bsm[brow][bko]   = o0;
        *(uint4*)&Bsm[brow][bko+8] = o1;
        __syncthreads();

        bf16x8 af[4], bf[4];
        #pragma unroll
        for (int s = 0; s < 4; ++s) af[s] = *(const bf16x8*)&Asm[mw + s*16 + fr][fq];
        #pragma unroll
        for (int t_ = 0; t_ < 4; ++t_) bf[t_] = *(const bf16x8*)&Bsm[nw + t_*16 + fr][fq];
        #pragma unroll
        for (int s = 0; s < 4; ++s)
            #pragma unroll
            for (int t_ = 0; t_ < 4; ++t_)
                acc[s][t_] = __builtin_amdgcn_mfma_f32_16x16x32_bf16(af[s], bf[t_], acc[s][t_], 0, 0, 0);
        __syncthreads();
    }

    const int cr = (l >> 4) * 4;
    const int cc = l & 15;
    const int tIdx = blockIdx.x;   // rows are t-major: row = t*128 + b
    #pragma unroll
    for (int t_ = 0; t_ < 4; ++t_){
        int col = n0 + nw + t_*16 + cc;
        float bias = bi1[col] + bi2[col];
        int gate = col >> 8;
        int j    = col & 255;
        size_t cbase = (size_t)tIdx*131072 + (size_t)(j>>4)*1024 + (size_t)(j&15)*4 + gate;
        #pragma unroll
        for (int s = 0; s < 4; ++s)
            #pragma unroll
            for (int r = 0; r < 4; ++r){
                int b = mw + s*16 + cr + r;
                pre2[cbase + (size_t)(b>>4)*16384 + ((b&15)>>2)*256 + (b&3)*64]
                    = f2b(acc[s][t_][r] + bias);
            }
    }
}

// --------------------- backward LSTM: one step from zero state (unchanged)
__global__ __launch_bounds__(256) void k_lstm_b(
    const __hip_bfloat16* __restrict__ feats255,
    const float* __restrict__ Wih_b,
    const float* __restrict__ bih_b, const float* __restrict__ bhh_b,
    float* __restrict__ h_b)
{
    __shared__ float fs[DD];
    const int tid = threadIdx.x;
    const int b = blockIdx.x;
    const unsigned* fbu = (const unsigned*)(feats255 + (size_t)b * DD);
    for (int i = tid; i < DD/2; i += 256){
        unsigned u = fbu[i];
        fs[2*i] = lo2f(u); fs[2*i+1] = hi2f(u);
    }
    __syncthreads();

    const int w = tid >> 6, lane = tid & 63;
    const int j = blockIdx.y * 4 + w;
    const float* Wi = Wih_b + (size_t)j * DD;
    const float* Wg = Wih_b + (size_t)(512 + j) * DD;
    const float* Wo = Wih_b + (size_t)(768 + j) * DD;
    float si = 0.f, sg = 0.f, so = 0.f;
    #pragma unroll 2
    for (int i = 0; i < 34; ++i){
        int k = lane + i*64;
        float f = fs[k];
        si += f * Wi[k]; sg += f * Wg[k]; so += f * Wo[k];
    }
    #pragma unroll
    for (int off = 32; off > 0; off >>= 1){
        si += __shfl_down(si, off);
        sg += __shfl_down(sg, off);
        so += __shfl_down(so, off);
    }
    if (lane == 0){
        float zi = si + bih_b[j]       + bhh_b[j];
        float zg = sg + bih_b[512 + j] + bhh_b[512 + j];
        float zo = so + bih_b[768 + j] + bhh_b[768 + j];
        float c = sigm(zi) * tanhf(zg);
        h_b[(size_t)b*LHID + j] = sigm(zo) * tanhf(c);
    }
}

// ------------------- forward LSTM R5: 16 waves, nt = gate, kc0-1 resident
#define MSTEP(kc, Bp) { \
    bf16x8 ah = *(const bf16x8*)&hAhi[tb][l15][(kc)*32 + q8]; \
    bf16x8 al = *(const bf16x8*)&hAlo[tb][l15][(kc)*32 + q8]; \
    _Pragma("unroll") for (int nt = 0; nt < 4; ++nt){ \
        acc[nt] = __builtin_amdgcn_mfma_f32_16x16x32_bf16(ah, (Bp)[nt], acc[nt], 0,0,0); \
        acc[nt] = __builtin_amdgcn_mfma_f32_16x16x32_bf16(al, (Bp)[nt], acc[nt], 0,0,0); } }

#define LDF(dst, kc) { _Pragma("unroll") for (int nt = 0; nt < 4; ++nt) \
    (dst)[nt] = *(const bf16x8*)(wtf + (((size_t)(w*32 + (kc)*4 + nt))*64 + l)*8); }

__global__ __launch_bounds__(1024, 4) void k_lstm_f4(
    const u16t* __restrict__ pre2,            // R5 permuted layout
    const __hip_bfloat16* __restrict__ WTfrag,
    float* __restrict__ hout)                 // (128,256)
{
    __shared__ u16t hAhi[2][16][264];
    __shared__ u16t hAlo[2][16][264];
    const int tid = threadIdx.x;
    const int w = tid >> 6, l = tid & 63;
    const int q = l >> 4, l15 = l & 15, q8 = q * 8;
    const int j = w*16 + l15;
    const int wg = blockIdx.x;
    const u16t* wtf = (const u16t*)WTfrag;

    for (int i = tid; i < 16*264; i += 1024){
        ((u16t*)hAhi[0])[i] = 0; ((u16t*)hAlo[0])[i] = 0;
        ((u16t*)hAhi[1])[i] = 0; ((u16t*)hAlo[1])[i] = 0;
    }

    bf16x8 Bres[2][4];
    LDF(Bres[0], 0);
    LDF(Bres[1], 1);
    bf16x8 Sa[4], Sb[4];
    LDF(Sa, 2); LDF(Sb, 3);
    float cst[4];
    #pragma unroll
    for (int i = 0; i < 4; ++i) cst[i] = 0.f;
    // pre2 lane base: wg*16384 + w*1024 + q*256 + r*64 + l15*4 (+ gate)
    const size_t pbase0 = (size_t)wg*16384 + (size_t)w*1024 + (size_t)q*256 + (size_t)l15*4;
    __syncthreads();

    #pragma unroll 1
    for (int t = 0; t < TT; ++t){
        const int tb = t & 1, bufn = tb ^ 1;
        union { uint2 v; u16t s[4]; } pr[4];
        {
            const u16t* pp = pre2 + (size_t)t*131072 + pbase0;
            #pragma unroll
            for (int r = 0; r < 4; ++r) pr[r].v = *(const uint2*)(pp + r*64);
        }

        f32x4 acc[4];
        #pragma unroll
        for (int nt = 0; nt < 4; ++nt) acc[nt] = (f32x4){0.f,0.f,0.f,0.f};

        MSTEP(0, Bres[0]);
        MSTEP(1, Bres[1]);
        MSTEP(2, Sa);  LDF(Sa, 4);
        MSTEP(3, Sb);  LDF(Sb, 5);
        MSTEP(4, Sa);  LDF(Sa, 6);
        MSTEP(5, Sb);  LDF(Sb, 7);
        MSTEP(6, Sa);  LDF(Sa, 2);   // prefetch next step
        MSTEP(7, Sb);  LDF(Sb, 3);   // prefetch next step

        #pragma unroll
        for (int r = 0; r < 4; ++r){
            float zi = acc[0][r] + b2f(pr[r].s[0]);
            float zf = acc[1][r] + b2f(pr[r].s[1]);
            float zg = acc[2][r] + b2f(pr[r].s[2]);
            float zo = acc[3][r] + b2f(pr[r].s[3]);
            float cn = fsig(zf)*cst[r] + fsig(zi)*ftanh(zg);
            cst[r] = cn;
            float hh = fsig(zo)*ftanh(cn);
            const int s = q*4 + r;
            u16t hb = f2b(hh);
            hAhi[bufn][s][j] = hb;
            hAlo[bufn][s][j] = f2b(hh - b2f(hb));
            if (t == TT-1)
                hout[((size_t)wg*16 + s)*LHID + j] = hh;
        }
        __syncthreads();
    }
}

// ----------------------------------------------------- head (unchanged)
__global__ __launch_bounds__(256) void k_head(
    const float* __restrict__ h_f, const float* __restrict__ h_b,
    const float* __restrict__ Wc, const float* __restrict__ bc,
    float* __restrict__ out)
{
    __shared__ float pool[512];
    const int b = blockIdx.x, tid = threadIdx.x;
    float p0 = fmaxf(h_f[(size_t)b*LHID + tid], 0.f);
    float p1 = fmaxf(h_b[(size_t)b*LHID + tid], 0.f);
    pool[tid] = p0; pool[256 + tid] = p1;
    out[(size_t)b*512 + tid]       = p0;
    out[(size_t)b*512 + 256 + tid] = p1;
    __syncthreads();
    for (int n = tid; n < NCLS; n += 256){
        float a = bc[n];
        const float* ww = Wc + (size_t)n * 512;
        #pragma unroll 4
        for (int k = 0; k < 512; k += 4){
            float4 wv = *(const float4*)(ww + k);
            a += pool[k]*wv.x + pool[k+1]*wv.y + pool[k+2]*wv.z + pool[k+3]*wv.w;
        }
        out[(size_t)BB*512 + (size_t)b*NCLS + n] = a;
    }
}

// ---------------------------------------------------------------------------
extern "C" void kernel_launch(void* const* d_in, const int* in_sizes, int n_in,
                              void* d_out, int out_size, void* d_ws, size_t ws_size,
                              hipStream_t stream) {
    const float* pose1 = (const float*)d_in[0];
    const float* pose2 = (const float*)d_in[1];
    const float* W1    = (const float*)d_in[2];
    const float* b1    = (const float*)d_in[3];
    const float* W2    = (const float*)d_in[4];
    const float* b2    = (const float*)d_in[5];
    const float* Wih_f = (const float*)d_in[6];
    const float* Whh_f = (const float*)d_in[7];
    const float* bih_f = (const float*)d_in[8];
    const float* bhh_f = (const float*)d_in[9];
    const float* Wih_b = (const float*)d_in[10];
    const float* bih_b = (const float*)d_in[12];
    const float* bhh_b = (const float*)d_in[13];
    const float* Wc    = (const float*)d_in[14];
    const float* bc    = (const float*)d_in[15];
    (void)in_sizes; (void)n_in; (void)out_size; (void)ws_size;
    float* out = (float*)d_out;
    char* ws = (char*)d_ws;

    // workspace (same 211,812,352-byte footprint)
    __hip_bfloat16* WTfrag = (__hip_bfloat16*)(ws + 0);           // 524,288
    __hip_bfloat16* W2Tb   = (__hip_bfloat16*)(ws + 524288);      //  32,768
    float*          h_b    = (float*)(ws + 557056);               // 131,072
    float*          h_f    = (float*)(ws + 688128);               // 131,072
    __hip_bfloat16* feats  = (__hip_bfloat16*)(ws + 2097152);     // 142,606,336
    u16t*           pre2   = (u16t*)(ws + 144703488);             //  67,108,864

    k_w2t     <<<64, 256, 0, stream>>>(W2, W2Tb);
    k_wfrag   <<<128, 256, 0, stream>>>(Whh_f, WTfrag);
    k_gcnfused<<<2048, 512, 0, stream>>>(pose1, pose2, W1, b1, b2, W2Tb, feats);
    k_gemm_mfma<<<dim3(256, 8), 256, 0, stream>>>(feats, Wih_f, bih_f, bhh_f, pre2);
    k_lstm_b  <<<dim3(128, 64), 256, 0, stream>>>(feats + (size_t)255*BB*DD, Wih_b, bih_b, bhh_b, h_b);
    k_lstm_f4 <<<8, 1024, 0, stream>>>(pre2, WTfrag, h_f);
    k_head    <<<128, 256, 0, stream>>>(h_f, h_b, Wc, bc, out);
}